// Round 1
// baseline (10048.734 us; speedup 1.0000x reference)
//
#include <hip/hip_runtime.h>
#include <math.h>

// Problem constants
constexpr int kB   = 32;     // batch
constexpr int kN   = 2048;   // raw points
constexpr int kG   = 128;    // groups (FPS centers)
constexpr int kM   = 32;     // group size (KNN)
constexpr int kC   = 384;    // trans dim
constexpr int kH   = 8;      // heads
constexpr int kHD  = 48;     // head dim
constexpr int kNT  = 129;    // tokens (CLS + groups)
constexpr int kMLP = 1536;
constexpr int kRows = kB * kNT; // 4128

// ---------------------------------------------------------------- FPS
// One block per batch. Exact fp32 replication of the reference scan:
// dist=min(dist, ||p-last||^2) (contract OFF, (dx2+dy2)+dz2 order), then
// argmax with first-index tie-break. idxs[t] = last *before* update.
__global__ __launch_bounds__(1024) void fps_kernel(
    const float* __restrict__ pts, float* __restrict__ center)
{
  #pragma clang fp contract(off)
  __shared__ float px[kN], py[kN], pz[kN], dist[kN];
  __shared__ float rv[16];
  __shared__ int   ri[16];
  __shared__ int   s_last;
  const int b = blockIdx.x, t = threadIdx.x;
  const float* P = pts + (size_t)b * kN * 3;
  for (int i = t; i < kN; i += 1024) {
    px[i] = P[3*i]; py[i] = P[3*i+1]; pz[i] = P[3*i+2];
    dist[i] = 1e10f;
  }
  __syncthreads();
  int last = 0;
  for (int it = 0; it < kG; ++it) {
    if (t == 0) {
      center[(size_t)(b*kG + it)*3 + 0] = px[last];
      center[(size_t)(b*kG + it)*3 + 1] = py[last];
      center[(size_t)(b*kG + it)*3 + 2] = pz[last];
    }
    const float lx = px[last], ly = py[last], lz = pz[last];
    float bestv = -1.0f; int besti = kN;
    for (int i = t; i < kN; i += 1024) {
      float dx = px[i]-lx, dy = py[i]-ly, dz = pz[i]-lz;
      float d = (dx*dx + dy*dy) + dz*dz;
      float nd = fminf(dist[i], d);
      dist[i] = nd;
      if (nd > bestv || (nd == bestv && i < besti)) { bestv = nd; besti = i; }
    }
    #pragma unroll
    for (int off = 32; off > 0; off >>= 1) {
      float vv = __shfl_down(bestv, off);
      int   ii = __shfl_down(besti, off);
      if (vv > bestv || (vv == bestv && ii < besti)) { bestv = vv; besti = ii; }
    }
    if ((t & 63) == 0) { rv[t>>6] = bestv; ri[t>>6] = besti; }
    __syncthreads();
    if (t == 0) {
      float bv = rv[0]; int bi = ri[0];
      for (int w = 1; w < 16; ++w)
        if (rv[w] > bv || (rv[w] == bv && ri[w] < bi)) { bv = rv[w]; bi = ri[w]; }
      s_last = bi;
    }
    __syncthreads();
    last = s_last;
  }
}

// ------------------------------------------------------- RoPE cos/sin table
__global__ void rope_kernel(const float* __restrict__ center,
                            float* __restrict__ pcs, float* __restrict__ psn)
{
  int idx = blockIdx.x*256 + threadIdx.x;
  if (idx >= kB*kG*24) return;
  int p  = idx % 24;
  int bg = idx / 24;
  int axis = p >> 3, j = p & 7;
  float e  = (float)(2*j) / 16.0f;
  float fr = 1.0f / powf(100.0f, e);
  float ang = center[(size_t)bg*3 + axis] * fr;
  pcs[idx] = cosf(ang);
  psn[idx] = sinf(ang);
}

// ---------------------------------------------------------------- KNN
// One block per (b,g). Exact d2, iterative 32x argmin with first-index
// tie-break (matches lax.top_k stability); order irrelevant (max-pooled).
__global__ __launch_bounds__(256) void knn_kernel(
    const float* __restrict__ pts, const float* __restrict__ center,
    float* __restrict__ neigh)
{
  #pragma clang fp contract(off)
  __shared__ float d2s[kN];
  __shared__ float rv[4];
  __shared__ int   ri[4];
  const int t = threadIdx.x;
  const int bg = blockIdx.x;
  const int b = bg >> 7;
  const float* P = pts + (size_t)b * kN * 3;
  const float cx = center[(size_t)bg*3+0];
  const float cy = center[(size_t)bg*3+1];
  const float cz = center[(size_t)bg*3+2];
  for (int i = t; i < kN; i += 256) {
    float dx = cx - P[3*i], dy = cy - P[3*i+1], dz = cz - P[3*i+2];
    d2s[i] = (dx*dx + dy*dy) + dz*dz;
  }
  __syncthreads();
  for (int m = 0; m < kM; ++m) {
    float bestv = 3.0e38f; int besti = kN;
    for (int i = t; i < kN; i += 256) {
      float v = d2s[i];
      if (v < bestv || (v == bestv && i < besti)) { bestv = v; besti = i; }
    }
    #pragma unroll
    for (int off = 32; off > 0; off >>= 1) {
      float vv = __shfl_down(bestv, off);
      int   ii = __shfl_down(besti, off);
      if (vv < bestv || (vv == bestv && ii < besti)) { bestv = vv; besti = ii; }
    }
    if ((t & 63) == 0) { rv[t>>6] = bestv; ri[t>>6] = besti; }
    __syncthreads();
    if (t == 0) {
      float bv = rv[0]; int bi = ri[0];
      for (int w = 1; w < 4; ++w)
        if (rv[w] < bv || (rv[w] == bv && ri[w] < bi)) { bv = rv[w]; bi = ri[w]; }
      d2s[bi] = 3.0e38f;
      float* o = neigh + ((size_t)bg*kM + m)*3;
      o[0] = P[3*bi+0] - cx; o[1] = P[3*bi+1] - cy; o[2] = P[3*bi+2] - cz;
    }
    __syncthreads();
  }
}

// ------------------------------------------------------------- encoder
// One block per group (4096 blocks, 256 thr). All intermediates in LDS
// (~113 KB). fg (broadcast half of concat) contributes an m-independent
// base term to layer3 -> halves layer3 FLOPs.
__global__ __launch_bounds__(256) void encoder_kernel(
    const float* __restrict__ neigh,
    const float* __restrict__ w1, const float* __restrict__ b1,
    const float* __restrict__ g1, const float* __restrict__ be1,
    const float* __restrict__ w2, const float* __restrict__ b2,
    const float* __restrict__ w3, const float* __restrict__ b3,
    const float* __restrict__ g2, const float* __restrict__ be2,
    const float* __restrict__ w4, const float* __restrict__ b4,
    float* __restrict__ x)
{
  __shared__ float xs[kM][4];
  __shared__ float f1[kM][128];
  __shared__ float f2[kM][256];
  __shared__ float fg[256];
  __shared__ float f3[kM][512];
  const int t = threadIdx.x;
  const int bg = blockIdx.x;
  const float* nb = neigh + (size_t)bg * (kM*3);
  if (t < kM*3) xs[t/3][t%3] = nb[t];
  __syncthreads();
  // layer 1: 3 -> 128, BN+ReLU
  for (int idx = t; idx < kM*128; idx += 256) {
    int m = idx >> 7, j = idx & 127;
    float s = xs[m][0]*w1[3*j] + xs[m][1]*w1[3*j+1] + xs[m][2]*w1[3*j+2] + b1[j];
    f1[m][j] = fmaxf(s * g1[j] + be1[j], 0.0f);
  }
  __syncthreads();
  // layer 2: 128 -> 256 (no BN/ReLU), then column max -> fg
  {
    const int j = t;
    float acc[kM];
    float bj = b2[j];
    #pragma unroll
    for (int m = 0; m < kM; ++m) acc[m] = bj;
    for (int k = 0; k < 128; k += 4) {
      float4 w = *(const float4*)(w2 + (size_t)j*128 + k);
      #pragma unroll
      for (int m = 0; m < kM; ++m) {
        float4 a = *(const float4*)(&f1[m][k]);
        acc[m] += a.x*w.x + a.y*w.y + a.z*w.z + a.w*w.w;
      }
    }
    float mx = acc[0];
    #pragma unroll
    for (int m = 1; m < kM; ++m) mx = fmaxf(mx, acc[m]);
    fg[j] = mx;
    #pragma unroll
    for (int m = 0; m < kM; ++m) f2[m][j] = acc[m];
  }
  __syncthreads();
  // layer 3: concat(512) -> 512, BN+ReLU.  cols j0=t, j1=t+256
  {
    const int j0 = t, j1 = t + 256;
    float base0 = b3[j0], base1 = b3[j1];
    for (int k = 0; k < 256; k += 4) {
      float4 f  = *(const float4*)(&fg[k]);
      float4 wa = *(const float4*)(w3 + (size_t)j0*512 + k);
      float4 wb = *(const float4*)(w3 + (size_t)j1*512 + k);
      base0 += f.x*wa.x + f.y*wa.y + f.z*wa.z + f.w*wa.w;
      base1 += f.x*wb.x + f.y*wb.y + f.z*wb.z + f.w*wb.w;
    }
    float acc0[kM], acc1[kM];
    #pragma unroll
    for (int m = 0; m < kM; ++m) { acc0[m] = base0; acc1[m] = base1; }
    for (int k = 0; k < 256; k += 4) {
      float4 wa = *(const float4*)(w3 + (size_t)j0*512 + 256 + k);
      float4 wb = *(const float4*)(w3 + (size_t)j1*512 + 256 + k);
      #pragma unroll
      for (int m = 0; m < kM; ++m) {
        float4 a = *(const float4*)(&f2[m][k]);
        acc0[m] += a.x*wa.x + a.y*wa.y + a.z*wa.z + a.w*wa.w;
        acc1[m] += a.x*wb.x + a.y*wb.y + a.z*wb.z + a.w*wb.w;
      }
    }
    float ga = g2[j0], ba = be2[j0], gb = g2[j1], bbv = be2[j1];
    #pragma unroll
    for (int m = 0; m < kM; ++m) {
      f3[m][j0] = fmaxf(acc0[m]*ga + ba, 0.0f);
      f3[m][j1] = fmaxf(acc1[m]*gb + bbv, 0.0f);
    }
  }
  __syncthreads();
  // layer 4: 512 -> 384, then max over points -> token
  {
    const bool two = (t < 128);
    const int j0 = t, j1 = t + 256;
    float acc0[kM], acc1[kM];
    float b0 = b4[j0], b1v = two ? b4[j1] : 0.0f;
    #pragma unroll
    for (int m = 0; m < kM; ++m) { acc0[m] = b0; acc1[m] = b1v; }
    for (int k = 0; k < 512; k += 4) {
      float4 wa = *(const float4*)(w4 + (size_t)j0*512 + k);
      float4 wb = make_float4(0.f,0.f,0.f,0.f);
      if (two) wb = *(const float4*)(w4 + (size_t)j1*512 + k);
      #pragma unroll
      for (int m = 0; m < kM; ++m) {
        float4 a = *(const float4*)(&f3[m][k]);
        acc0[m] += a.x*wa.x + a.y*wa.y + a.z*wa.z + a.w*wa.w;
        if (two) acc1[m] += a.x*wb.x + a.y*wb.y + a.z*wb.z + a.w*wb.w;
      }
    }
    float mx0 = acc0[0], mx1 = acc1[0];
    #pragma unroll
    for (int m = 1; m < kM; ++m) { mx0 = fmaxf(mx0, acc0[m]); mx1 = fmaxf(mx1, acc1[m]); }
    const int b = bg >> 7, g = bg & 127;
    float* orow = x + ((size_t)b*kNT + 1 + g) * kC;
    orow[j0] = mx0;
    if (two) orow[j1] = mx1;
  }
}

// ----------------------------------------------------------- CLS token init
__global__ void cls_kernel(const float* __restrict__ ct, const float* __restrict__ cp,
                           float* __restrict__ x)
{
  int idx = blockIdx.x*256 + threadIdx.x;
  if (idx >= kB*kC) return;
  int b = idx / kC, c = idx % kC;
  x[(size_t)b*kNT*kC + c] = ct[c] + cp[c];
}

// ------------------------------------------------------------- LayerNorm
// One wave per row (4 rows/block).
__global__ __launch_bounds__(256) void ln_kernel(
    const float* __restrict__ in, float* __restrict__ out,
    const float* __restrict__ g, const float* __restrict__ bb)
{
  const int t = threadIdx.x;
  const int lane = t & 63;
  const int row = blockIdx.x*4 + (t >> 6);
  const float* p = in + (size_t)row*kC;
  float v[6];
  #pragma unroll
  for (int k = 0; k < 6; ++k) v[k] = p[k*64 + lane];
  float s = 0.f;
  #pragma unroll
  for (int k = 0; k < 6; ++k) s += v[k];
  #pragma unroll
  for (int off = 1; off < 64; off <<= 1) s += __shfl_xor(s, off);
  float mean = s / 384.0f;
  float vs = 0.f;
  #pragma unroll
  for (int k = 0; k < 6; ++k) { float d = v[k]-mean; vs += d*d; }
  #pragma unroll
  for (int off = 1; off < 64; off <<= 1) vs += __shfl_xor(vs, off);
  float r = rsqrtf(vs / 384.0f + 1e-5f);
  float* o = out + (size_t)row*kC;
  #pragma unroll
  for (int k = 0; k < 6; ++k) {
    int c = k*64 + lane;
    o[c] = (v[k]-mean)*r*g[c] + bb[c];
  }
}

// ------------------------------------------------------------- GEMM
// Out[M,N] = A[M,K] @ W[N,K]^T (+epilogue). 128x64 tile, BK=16, 256 thr,
// 8x4 per thread. EPI: 0 none, 1 bias+residual, 2 bias+exact-GELU.
template <int EPI>
__global__ __launch_bounds__(256) void gemm_kernel(
    const float* __restrict__ A, const float* __restrict__ W,
    float* Co, const float* __restrict__ bias,
    const float* res, int Mm, int Nn, int Kk)
{
  __shared__ float As[16][132];
  __shared__ float Ws[16][68];
  const int t  = threadIdx.x;
  const int m0 = blockIdx.x * 128;
  const int n0 = blockIdx.y * 64;
  const int tx = t & 15, ty = t >> 4;
  const int ar = t >> 2;
  const int ak = (t & 3) * 4;
  float acc[8][4] = {};
  for (int k0 = 0; k0 < Kk; k0 += 16) {
    #pragma unroll
    for (int rr = 0; rr < 2; ++rr) {
      int r = ar + rr*64;
      int grow = m0 + r;
      float4 av = make_float4(0.f,0.f,0.f,0.f);
      if (grow < Mm) av = *(const float4*)(A + (size_t)grow*Kk + k0 + ak);
      As[ak+0][r] = av.x; As[ak+1][r] = av.y; As[ak+2][r] = av.z; As[ak+3][r] = av.w;
    }
    {
      int n = t >> 2;
      float4 wv = *(const float4*)(W + (size_t)(n0+n)*Kk + k0 + ak);
      Ws[ak+0][n] = wv.x; Ws[ak+1][n] = wv.y; Ws[ak+2][n] = wv.z; Ws[ak+3][n] = wv.w;
    }
    __syncthreads();
    #pragma unroll
    for (int k = 0; k < 16; ++k) {
      float4 a0 = *(const float4*)(&As[k][ty*8]);
      float4 a1 = *(const float4*)(&As[k][ty*8+4]);
      float4 b0 = *(const float4*)(&Ws[k][tx*4]);
      float a[8] = {a0.x,a0.y,a0.z,a0.w,a1.x,a1.y,a1.z,a1.w};
      float bv[4] = {b0.x,b0.y,b0.z,b0.w};
      #pragma unroll
      for (int i = 0; i < 8; ++i)
        #pragma unroll
        for (int j = 0; j < 4; ++j)
          acc[i][j] += a[i]*bv[j];
    }
    __syncthreads();
  }
  #pragma unroll
  for (int i = 0; i < 8; ++i) {
    int r = m0 + ty*8 + i;
    if (r < Mm) {
      #pragma unroll
      for (int j = 0; j < 4; ++j) {
        int c = n0 + tx*4 + j;
        size_t o = (size_t)r*Nn + c;
        float v = acc[i][j];
        if constexpr (EPI == 0) {
          Co[o] = v;
        } else if constexpr (EPI == 1) {
          Co[o] = res[o] + v + bias[c];
        } else {
          v += bias[c];
          Co[o] = 0.5f*v*(1.0f + erff(v*0.70710678118654752440f));
        }
      }
    }
  }
}

// ------------------------------------------------------------- attention
// One block per (b,h), 512 thr. Stages Q,K,V in LDS with Givens+RoPE
// applied on the fly; one wave per query row.
__global__ __launch_bounds__(512) void attn_kernel(
    const float* __restrict__ qkv, const float* __restrict__ pcs,
    const float* __restrict__ psn, const float* __restrict__ gth,
    float* __restrict__ o)
{
  __shared__ float qs[kNT][kHD];
  __shared__ float ks[kNT][kHD];
  __shared__ float vls[kNT][kHD];
  __shared__ float gcs[24], gss[24];
  __shared__ float ps[8][132];
  const int t = threadIdx.x;
  const int bh = blockIdx.x;
  const int b = bh >> 3, hh = bh & 7;
  if (t < 24) { float th = gth[hh*24 + t]; gcs[t] = cosf(th); gss[t] = sinf(th); }
  __syncthreads();
  for (int idx = t; idx < kNT*24; idx += 512) {
    int n = idx / 24, p = idx % 24;
    const float* base = qkv + ((size_t)(b*kNT + n))*1152 + hh*kHD + 2*p;
    float q0 = base[0],   q1 = base[1];
    float k0 = base[384], k1 = base[385];
    float v0 = base[768], v1 = base[769];
    float cg = gcs[p], sg = gss[p];
    float qr = q0*cg - q1*sg, qi = q0*sg + q1*cg;
    float kr = k0*cg - k1*sg, ki = k0*sg + k1*cg;
    if (n > 0) {
      size_t pi = ((size_t)b*kG + (n-1))*24 + p;
      float pc = pcs[pi], pv = psn[pi];
      float tq = qr*pc - qi*pv; qi = qr*pv + qi*pc; qr = tq;
      float tk = kr*pc - ki*pv; ki = kr*pv + ki*pc; kr = tk;
    }
    qs[n][2*p] = qr; qs[n][2*p+1] = qi;
    ks[n][2*p] = kr; ks[n][2*p+1] = ki;
    vls[n][2*p] = v0; vls[n][2*p+1] = v1;
  }
  __syncthreads();
  const int lane = t & 63, w = t >> 6;
  for (int r = w; r < kNT; r += 8) {
    float4 q[12];
    #pragma unroll
    for (int d = 0; d < 12; ++d) q[d] = *(const float4*)(&qs[r][d*4]);
    float sv[3];
    float mx = -3.0e38f;
    #pragma unroll
    for (int ji = 0; ji < 3; ++ji) {
      int j = ji*64 + lane;
      float s = -3.0e38f;
      if (j < kNT) {
        float acc = 0.f;
        #pragma unroll
        for (int d = 0; d < 12; ++d) {
          float4 kv = *(const float4*)(&ks[j][d*4]);
          acc += q[d].x*kv.x + q[d].y*kv.y + q[d].z*kv.z + q[d].w*kv.w;
        }
        s = acc * 0.14433756729740643f;
      }
      sv[ji] = s;
      mx = fmaxf(mx, s);
    }
    #pragma unroll
    for (int off = 1; off < 64; off <<= 1) mx = fmaxf(mx, __shfl_xor(mx, off));
    float sum = 0.f;
    #pragma unroll
    for (int ji = 0; ji < 3; ++ji) {
      int j = ji*64 + lane;
      if (j < kNT) { float e = expf(sv[ji] - mx); ps[w][j] = e; sum += e; }
    }
    #pragma unroll
    for (int off = 1; off < 64; off <<= 1) sum += __shfl_xor(sum, off);
    if (lane < kHD) {
      float accv = 0.f;
      for (int j4 = 0; j4 < 128; j4 += 4) {
        float4 pv = *(const float4*)(&ps[w][j4]);
        accv += pv.x*vls[j4][lane] + pv.y*vls[j4+1][lane]
              + pv.z*vls[j4+2][lane] + pv.w*vls[j4+3][lane];
      }
      accv += ps[w][128]*vls[128][lane];
      o[((size_t)(b*kNT + r))*kC + hh*kHD + lane] = accv / sum;
    }
  }
}

// ------------------------------------------------------------- head
// One block per batch row: feat = [cls | max over groups], then
// BN-ReLU MLP 768->256->256->40.
__global__ __launch_bounds__(256) void head_kernel(
    const float* __restrict__ xf,
    const float* __restrict__ hw1, const float* __restrict__ hb1,
    const float* __restrict__ hg1, const float* __restrict__ hbe1,
    const float* __restrict__ hw2, const float* __restrict__ hb2,
    const float* __restrict__ hg2, const float* __restrict__ hbe2,
    const float* __restrict__ hw3, const float* __restrict__ hb3,
    float* __restrict__ out)
{
  __shared__ float f[768];
  __shared__ float h1[256], h2[256];
  const int t = threadIdx.x;
  const int b = blockIdx.x;
  const float* xb = xf + (size_t)b*kNT*kC;
  for (int c = t; c < kC; c += 256) {
    f[c] = xb[c];
    float mx = -3.0e38f;
    for (int n = 1; n < kNT; ++n) mx = fmaxf(mx, xb[(size_t)n*kC + c]);
    f[kC + c] = mx;
  }
  __syncthreads();
  {
    float acc = hb1[t];
    for (int k = 0; k < 768; k += 4) {
      float4 wv = *(const float4*)(hw1 + (size_t)t*768 + k);
      float4 fv = *(const float4*)(&f[k]);
      acc += fv.x*wv.x + fv.y*wv.y + fv.z*wv.z + fv.w*wv.w;
    }
    h1[t] = fmaxf(acc*hg1[t] + hbe1[t], 0.0f);
  }
  __syncthreads();
  {
    float acc = hb2[t];
    for (int k = 0; k < 256; k += 4) {
      float4 wv = *(const float4*)(hw2 + (size_t)t*256 + k);
      float4 fv = *(const float4*)(&h1[k]);
      acc += fv.x*wv.x + fv.y*wv.y + fv.z*wv.z + fv.w*wv.w;
    }
    h2[t] = fmaxf(acc*hg2[t] + hbe2[t], 0.0f);
  }
  __syncthreads();
  if (t < 40) {
    float acc = hb3[t];
    for (int k = 0; k < 256; k += 4) {
      float4 wv = *(const float4*)(hw3 + (size_t)t*256 + k);
      float4 fv = *(const float4*)(&h2[k]);
      acc += fv.x*wv.x + fv.y*wv.y + fv.z*wv.z + fv.w*wv.w;
    }
    out[(size_t)b*40 + t] = acc;
  }
}

// ------------------------------------------------------------- launch
extern "C" void kernel_launch(void* const* d_in, const int* in_sizes, int n_in,
                              void* d_out, int out_size, void* d_ws, size_t ws_size,
                              hipStream_t stream) {
  const float* pts     = (const float*)d_in[0];
  const float* enc_w1  = (const float*)d_in[1];
  const float* enc_b1  = (const float*)d_in[2];
  const float* enc_g1  = (const float*)d_in[3];
  const float* enc_be1 = (const float*)d_in[4];
  const float* enc_w2  = (const float*)d_in[5];
  const float* enc_b2  = (const float*)d_in[6];
  const float* enc_w3  = (const float*)d_in[7];
  const float* enc_b3  = (const float*)d_in[8];
  const float* enc_g2  = (const float*)d_in[9];
  const float* enc_be2 = (const float*)d_in[10];
  const float* enc_w4  = (const float*)d_in[11];
  const float* enc_b4  = (const float*)d_in[12];
  const float* cls_tok = (const float*)d_in[13];
  const float* cls_pos = (const float*)d_in[14];
  const float* ln1_g   = (const float*)d_in[15];
  const float* ln1_b   = (const float*)d_in[16];
  const float* qkv_w   = (const float*)d_in[17];
  const float* givens  = (const float*)d_in[18];
  const float* proj_w  = (const float*)d_in[19];
  const float* proj_b  = (const float*)d_in[20];
  const float* ln2_g   = (const float*)d_in[21];
  const float* ln2_b   = (const float*)d_in[22];
  const float* fc1_w   = (const float*)d_in[23];
  const float* fc1_b   = (const float*)d_in[24];
  const float* fc2_w   = (const float*)d_in[25];
  const float* fc2_b   = (const float*)d_in[26];
  const float* norm_g  = (const float*)d_in[27];
  const float* norm_b  = (const float*)d_in[28];
  const float* hw1     = (const float*)d_in[29];
  const float* hb1     = (const float*)d_in[30];
  const float* hg1     = (const float*)d_in[31];
  const float* hbe1    = (const float*)d_in[32];
  const float* hw2     = (const float*)d_in[33];
  const float* hb2     = (const float*)d_in[34];
  const float* hg2     = (const float*)d_in[35];
  const float* hbe2    = (const float*)d_in[36];
  const float* hw3     = (const float*)d_in[37];
  const float* hb3     = (const float*)d_in[38];

  float* ws = (float*)d_ws;
  size_t off = 0;
  float* center = ws + off; off += (size_t)kB*kG*3;        // 12288
  float* pcs    = ws + off; off += (size_t)kB*kG*24;       // 98304
  float* psn    = ws + off; off += (size_t)kB*kG*24;       // 98304
  float* neigh  = ws + off; off += (size_t)kB*kG*kM*3;     // 393216
  float* xbuf   = ws + off; off += (size_t)kRows*kC;       // 1585152
  float* hbuf   = ws + off; off += (size_t)kRows*kC;       // 1585152
  float* big    = ws + off; off += (size_t)kRows*kMLP;     // 6340608 (qkv & mlp)

  fps_kernel<<<kB, 1024, 0, stream>>>(pts, center);
  rope_kernel<<<(kB*kG*24 + 255)/256, 256, 0, stream>>>(center, pcs, psn);
  knn_kernel<<<kB*kG, 256, 0, stream>>>(pts, center, neigh);
  encoder_kernel<<<kB*kG, 256, 0, stream>>>(neigh,
      enc_w1, enc_b1, enc_g1, enc_be1, enc_w2, enc_b2,
      enc_w3, enc_b3, enc_g2, enc_be2, enc_w4, enc_b4, xbuf);
  cls_kernel<<<(kB*kC + 255)/256, 256, 0, stream>>>(cls_tok, cls_pos, xbuf);

  const int lnGrid = kRows/4;
  for (int l = 0; l < 12; ++l) {
    ln_kernel<<<lnGrid, 256, 0, stream>>>(xbuf, hbuf, ln1_g + l*kC, ln1_b + l*kC);
    gemm_kernel<0><<<dim3(33, 18), 256, 0, stream>>>(
        hbuf, qkv_w + (size_t)l*1152*kC, big, nullptr, nullptr, kRows, 1152, kC);
    attn_kernel<<<kB*kH, 512, 0, stream>>>(big, pcs, psn, givens + (size_t)l*kH*24, hbuf);
    gemm_kernel<1><<<dim3(33, 6), 256, 0, stream>>>(
        hbuf, proj_w + (size_t)l*kC*kC, xbuf, proj_b + l*kC, xbuf, kRows, kC, kC);
    ln_kernel<<<lnGrid, 256, 0, stream>>>(xbuf, hbuf, ln2_g + l*kC, ln2_b + l*kC);
    gemm_kernel<2><<<dim3(33, 24), 256, 0, stream>>>(
        hbuf, fc1_w + (size_t)l*kMLP*kC, big, fc1_b + l*kMLP, nullptr, kRows, kMLP, kC);
    gemm_kernel<1><<<dim3(33, 6), 256, 0, stream>>>(
        big, fc2_w + (size_t)l*kC*kMLP, xbuf, fc2_b + l*kC, xbuf, kRows, kC, kMLP);
  }
  ln_kernel<<<lnGrid, 256, 0, stream>>>(xbuf, hbuf, norm_g, norm_b);
  head_kernel<<<kB, 256, 0, stream>>>(hbuf,
      hw1, hb1, hg1, hbe1, hw2, hb2, hg2, hbe2, hw3, hb3, (float*)d_out);
}

// Round 2
// 3356.655 us; speedup vs baseline: 2.9937x; 2.9937x over previous
//
#include <hip/hip_runtime.h>
#include <math.h>

// Problem constants
constexpr int kB   = 32;     // batch
constexpr int kN   = 2048;   // raw points
constexpr int kG   = 128;    // groups (FPS centers)
constexpr int kM   = 32;     // group size (KNN)
constexpr int kC   = 384;    // trans dim
constexpr int kH   = 8;      // heads
constexpr int kHD  = 48;     // head dim
constexpr int kNT  = 129;    // tokens (CLS + groups)
constexpr int kMLP = 1536;
constexpr int kRows = kB * kNT; // 4128
constexpr int kGC  = 512;       // encoder groups per chunk
constexpr int kRC  = kGC * kM;  // encoder rows per chunk = 16384

typedef __attribute__((ext_vector_type(8))) short bf16x8;
typedef __attribute__((ext_vector_type(4))) float f32x4;

__device__ __forceinline__ unsigned short f2bf(float x) {
  unsigned u = __float_as_uint(x);
  unsigned r = (u + 0x7fffu + ((u >> 16) & 1u)) >> 16;
  return (unsigned short)r;
}
__device__ __forceinline__ float bf2f(unsigned short u) {
  return __uint_as_float(((unsigned)u) << 16);
}

// ---------------------------------------------------------------- FPS
__global__ __launch_bounds__(1024) void fps_kernel(
    const float* __restrict__ pts, float* __restrict__ center)
{
  #pragma clang fp contract(off)
  __shared__ float px[kN], py[kN], pz[kN], dist[kN];
  __shared__ float rv[16];
  __shared__ int   ri[16];
  __shared__ int   s_last;
  const int b = blockIdx.x, t = threadIdx.x;
  const float* P = pts + (size_t)b * kN * 3;
  for (int i = t; i < kN; i += 1024) {
    px[i] = P[3*i]; py[i] = P[3*i+1]; pz[i] = P[3*i+2];
    dist[i] = 1e10f;
  }
  __syncthreads();
  int last = 0;
  for (int it = 0; it < kG; ++it) {
    if (t == 0) {
      center[(size_t)(b*kG + it)*3 + 0] = px[last];
      center[(size_t)(b*kG + it)*3 + 1] = py[last];
      center[(size_t)(b*kG + it)*3 + 2] = pz[last];
    }
    const float lx = px[last], ly = py[last], lz = pz[last];
    float bestv = -1.0f; int besti = kN;
    for (int i = t; i < kN; i += 1024) {
      float dx = px[i]-lx, dy = py[i]-ly, dz = pz[i]-lz;
      float d = (dx*dx + dy*dy) + dz*dz;
      float nd = fminf(dist[i], d);
      dist[i] = nd;
      if (nd > bestv || (nd == bestv && i < besti)) { bestv = nd; besti = i; }
    }
    #pragma unroll
    for (int off = 32; off > 0; off >>= 1) {
      float vv = __shfl_down(bestv, off);
      int   ii = __shfl_down(besti, off);
      if (vv > bestv || (vv == bestv && ii < besti)) { bestv = vv; besti = ii; }
    }
    if ((t & 63) == 0) { rv[t>>6] = bestv; ri[t>>6] = besti; }
    __syncthreads();
    if (t == 0) {
      float bv = rv[0]; int bi = ri[0];
      for (int w = 1; w < 16; ++w)
        if (rv[w] > bv || (rv[w] == bv && ri[w] < bi)) { bv = rv[w]; bi = ri[w]; }
      s_last = bi;
    }
    __syncthreads();
    last = s_last;
  }
}

// ------------------------------------------------------- RoPE cos/sin table
__global__ void rope_kernel(const float* __restrict__ center,
                            float* __restrict__ pcs, float* __restrict__ psn)
{
  int idx = blockIdx.x*256 + threadIdx.x;
  if (idx >= kB*kG*24) return;
  int p  = idx % 24;
  int bg = idx / 24;
  int axis = p >> 3, j = p & 7;
  float e  = (float)(2*j) / 16.0f;
  float fr = 1.0f / powf(100.0f, e);
  float ang = center[(size_t)bg*3 + axis] * fr;
  pcs[idx] = cosf(ang);
  psn[idx] = sinf(ang);
}

// ---------------------------------------------------------------- KNN
__global__ __launch_bounds__(256) void knn_kernel(
    const float* __restrict__ pts, const float* __restrict__ center,
    float* __restrict__ neigh)
{
  #pragma clang fp contract(off)
  __shared__ float d2s[kN];
  __shared__ float rv[4];
  __shared__ int   ri[4];
  const int t = threadIdx.x;
  const int bg = blockIdx.x;
  const int b = bg >> 7;
  const float* P = pts + (size_t)b * kN * 3;
  const float cx = center[(size_t)bg*3+0];
  const float cy = center[(size_t)bg*3+1];
  const float cz = center[(size_t)bg*3+2];
  for (int i = t; i < kN; i += 256) {
    float dx = cx - P[3*i], dy = cy - P[3*i+1], dz = cz - P[3*i+2];
    d2s[i] = (dx*dx + dy*dy) + dz*dz;
  }
  __syncthreads();
  for (int m = 0; m < kM; ++m) {
    float bestv = 3.0e38f; int besti = kN;
    for (int i = t; i < kN; i += 256) {
      float v = d2s[i];
      if (v < bestv || (v == bestv && i < besti)) { bestv = v; besti = i; }
    }
    #pragma unroll
    for (int off = 32; off > 0; off >>= 1) {
      float vv = __shfl_down(bestv, off);
      int   ii = __shfl_down(besti, off);
      if (vv < bestv || (vv == bestv && ii < besti)) { bestv = vv; besti = ii; }
    }
    if ((t & 63) == 0) { rv[t>>6] = bestv; ri[t>>6] = besti; }
    __syncthreads();
    if (t == 0) {
      float bv = rv[0]; int bi = ri[0];
      for (int w = 1; w < 4; ++w)
        if (rv[w] < bv || (rv[w] == bv && ri[w] < bi)) { bv = rv[w]; bi = ri[w]; }
      d2s[bi] = 3.0e38f;
      float* o = neigh + ((size_t)bg*kM + m)*3;
      o[0] = P[3*bi+0] - cx; o[1] = P[3*bi+1] - cy; o[2] = P[3*bi+2] - cz;
    }
    __syncthreads();
  }
}

// ------------------------------------------------- encoder layer1 (3->128)
// 2 rows per block (256 thr). Writes bf16.
__global__ __launch_bounds__(256) void enc1_kernel(
    const float* __restrict__ neighC,
    const float* __restrict__ w1, const float* __restrict__ b1,
    const float* __restrict__ g1, const float* __restrict__ be1,
    unsigned short* __restrict__ f1c)
{
  const int t = threadIdx.x;
  const int r = blockIdx.x*2 + (t >> 7);
  const int c = t & 127;
  const float* nr = neighC + (size_t)r*3;
  float x0 = nr[0], x1 = nr[1], x2 = nr[2];
  float s = x0*w1[3*c] + x1*w1[3*c+1] + x2*w1[3*c+2] + b1[c];
  float v = fmaxf(s*g1[c] + be1[c], 0.0f);
  f1c[(size_t)r*128 + c] = f2bf(v);
}

// ------------------------------------------------- encoder fg pool (layer2 max)
// block = one group; 256 threads = 256 cols. max over 32 rows.
__global__ __launch_bounds__(256) void pool2_kernel(
    const unsigned short* __restrict__ f2c, unsigned short* __restrict__ fgc)
{
  const int g = blockIdx.x, c = threadIdx.x;
  float mx = -3.0e38f;
  #pragma unroll 8
  for (int m = 0; m < kM; ++m)
    mx = fmaxf(mx, bf2f(f2c[((size_t)g*kM + m)*256 + c]));
  fgc[(size_t)g*256 + c] = f2bf(mx);
}

// ------------------------------------------------------------- MFMA GEMM
// Out[M,N] (+epilogue) = A[M,K](bf16,lda) @ B[N,K](fp32,ldb)^T
// 128x128 tile, BK=64, 256 thr = 4 waves in 2x2, each wave 64x64 (4x4 frags).
// EPI: 0 bf16 plain | 1 bf16 +bias | 2 f32 +bias | 3 bf16 relu((v+base[r>>5])*g+be)
//      4 fused 32-row max-pool (+bias) -> tokens | 5 f32 res+v+bias | 6 bf16 gelu(v+bias)
template <int EPI>
__global__ __launch_bounds__(256) void mgemm_kernel(
    const unsigned short* __restrict__ A, int lda,
    const float* __restrict__ B, int ldb,
    void* __restrict__ Cv,
    const float* __restrict__ bias,
    const float* __restrict__ aux,       // res (EPI5) or base (EPI3)
    const float* __restrict__ gsc, const float* __restrict__ bsc,  // EPI3
    int Mm, int Nn, int Kk,
    float* __restrict__ poolOut, int poolG0)
{
  __shared__ unsigned short As[128][72];
  __shared__ unsigned short Bs[128][72];
  const int t = threadIdx.x;
  const int m0 = blockIdx.x * 128;
  const int n0 = blockIdx.y * 128;
  const int w = t >> 6, lane = t & 63;
  const int wm = w >> 1, wn = w & 1;
  const int lr = lane & 15;
  const int lk = (lane >> 4) * 8;
  const int srow = t >> 3;          // 0..31
  const int skseg = (t & 7) * 8;    // 0..56
  f32x4 acc[4][4] = {};
  for (int k0 = 0; k0 < Kk; k0 += 64) {
    #pragma unroll
    for (int p = 0; p < 4; ++p) {
      int r = p*32 + srow;
      int gr = m0 + r;
      bf16x8 av = {};
      if (gr < Mm) av = *(const bf16x8*)(A + (size_t)gr*lda + k0 + skseg);
      *(bf16x8*)(&As[r][skseg]) = av;
    }
    #pragma unroll
    for (int p = 0; p < 4; ++p) {
      int r = p*32 + srow;
      const float* bp = B + (size_t)(n0 + r)*ldb + k0 + skseg;
      float4 b0 = *(const float4*)(bp);
      float4 b1 = *(const float4*)(bp + 4);
      bf16x8 bv;
      bv[0] = (short)f2bf(b0.x); bv[1] = (short)f2bf(b0.y);
      bv[2] = (short)f2bf(b0.z); bv[3] = (short)f2bf(b0.w);
      bv[4] = (short)f2bf(b1.x); bv[5] = (short)f2bf(b1.y);
      bv[6] = (short)f2bf(b1.z); bv[7] = (short)f2bf(b1.w);
      *(bf16x8*)(&Bs[r][skseg]) = bv;
    }
    __syncthreads();
    #pragma unroll
    for (int kk = 0; kk < 64; kk += 32) {
      bf16x8 af[4], bf[4];
      #pragma unroll
      for (int i = 0; i < 4; ++i)
        af[i] = *(const bf16x8*)(&As[wm*64 + i*16 + lr][kk + lk]);
      #pragma unroll
      for (int i = 0; i < 4; ++i)
        bf[i] = *(const bf16x8*)(&Bs[wn*64 + i*16 + lr][kk + lk]);
      #pragma unroll
      for (int i = 0; i < 4; ++i)
        #pragma unroll
        for (int j = 0; j < 4; ++j)
          acc[i][j] = __builtin_amdgcn_mfma_f32_16x16x32_bf16(af[i], bf[j], acc[i][j], 0, 0, 0);
    }
    __syncthreads();
  }

  if constexpr (EPI == 4) {
    // fused max-pool over 32-row groups (Mm multiple of 128 guaranteed)
    #pragma unroll
    for (int ni = 0; ni < 4; ++ni) {
      int cc = n0 + wn*64 + ni*16 + lr;
      float bcol = bias[cc];
      #pragma unroll
      for (int gg = 0; gg < 2; ++gg) {
        float mx = -3.0e38f;
        #pragma unroll
        for (int mi = 2*gg; mi < 2*gg + 2; ++mi)
          #pragma unroll
          for (int j = 0; j < 4; ++j)
            mx = fmaxf(mx, acc[mi][ni][j]);
        mx = fmaxf(mx, __shfl_xor(mx, 16));
        mx = fmaxf(mx, __shfl_xor(mx, 32));
        if ((lane >> 4) == 0) {
          int ggl = poolG0 + (m0 >> 5) + wm*2 + gg;
          int b = ggl >> 7, g = ggl & 127;
          poolOut[((size_t)b*kNT + 1 + g)*kC + cc] = mx + bcol;
        }
      }
    }
    return;
  }

  #pragma unroll
  for (int mi = 0; mi < 4; ++mi) {
    #pragma unroll
    for (int j = 0; j < 4; ++j) {
      int r = m0 + wm*64 + mi*16 + (lane >> 4)*4 + j;
      if (r < Mm) {
        #pragma unroll
        for (int ni = 0; ni < 4; ++ni) {
          int cc = n0 + wn*64 + ni*16 + lr;
          float v = acc[mi][ni][j];
          size_t o = (size_t)r*Nn + cc;
          if constexpr (EPI == 0) {
            ((unsigned short*)Cv)[o] = f2bf(v);
          } else if constexpr (EPI == 1) {
            ((unsigned short*)Cv)[o] = f2bf(v + bias[cc]);
          } else if constexpr (EPI == 2) {
            ((float*)Cv)[o] = v + bias[cc];
          } else if constexpr (EPI == 3) {
            float u = (v + aux[(size_t)(r >> 5)*Nn + cc])*gsc[cc] + bsc[cc];
            ((unsigned short*)Cv)[o] = f2bf(fmaxf(u, 0.0f));
          } else if constexpr (EPI == 5) {
            ((float*)Cv)[o] = aux[o] + v + bias[cc];
          } else {
            float u = v + bias[cc];
            ((unsigned short*)Cv)[o] = f2bf(0.5f*u*(1.0f + erff(u*0.70710678118654752440f)));
          }
        }
      }
    }
  }
}

// ----------------------------------------------------------- CLS token init
__global__ void cls_kernel(const float* __restrict__ ct, const float* __restrict__ cp,
                           float* __restrict__ x)
{
  int idx = blockIdx.x*256 + threadIdx.x;
  if (idx >= kB*kC) return;
  int b = idx / kC, c = idx % kC;
  x[(size_t)b*kNT*kC + c] = ct[c] + cp[c];
}

// ------------------------------------------------------------- LayerNorm
// One wave per row (4 rows/block). OUTBF: 1 -> bf16, 0 -> f32.
template <int OUTBF>
__global__ __launch_bounds__(256) void ln_kernel(
    const float* __restrict__ in, void* __restrict__ outv,
    const float* __restrict__ g, const float* __restrict__ bb)
{
  const int t = threadIdx.x;
  const int lane = t & 63;
  const int row = blockIdx.x*4 + (t >> 6);
  const float* p = in + (size_t)row*kC;
  float v[6];
  #pragma unroll
  for (int k = 0; k < 6; ++k) v[k] = p[k*64 + lane];
  float s = 0.f;
  #pragma unroll
  for (int k = 0; k < 6; ++k) s += v[k];
  #pragma unroll
  for (int off = 1; off < 64; off <<= 1) s += __shfl_xor(s, off);
  float mean = s / 384.0f;
  float vs = 0.f;
  #pragma unroll
  for (int k = 0; k < 6; ++k) { float d = v[k]-mean; vs += d*d; }
  #pragma unroll
  for (int off = 1; off < 64; off <<= 1) vs += __shfl_xor(vs, off);
  float r = rsqrtf(vs / 384.0f + 1e-5f);
  #pragma unroll
  for (int k = 0; k < 6; ++k) {
    int c = k*64 + lane;
    float o = (v[k]-mean)*r*g[c] + bb[c];
    if constexpr (OUTBF) ((unsigned short*)outv)[(size_t)row*kC + c] = f2bf(o);
    else                 ((float*)outv)[(size_t)row*kC + c] = o;
  }
}

// ------------------------------------------------------------- attention
// One block per (b,h), 512 thr. bf16 qkv in, bf16 out; fp32 math inside.
__global__ __launch_bounds__(512) void attn_kernel(
    const unsigned short* __restrict__ qkv, const float* __restrict__ pcs,
    const float* __restrict__ psn, const float* __restrict__ gth,
    unsigned short* __restrict__ o)
{
  __shared__ float qs[kNT][kHD];
  __shared__ float ks[kNT][kHD];
  __shared__ float vls[kNT][kHD];
  __shared__ float gcs[24], gss[24];
  __shared__ float ps[8][132];
  const int t = threadIdx.x;
  const int bh = blockIdx.x;
  const int b = bh >> 3, hh = bh & 7;
  if (t < 24) { float th = gth[hh*24 + t]; gcs[t] = cosf(th); gss[t] = sinf(th); }
  __syncthreads();
  for (int idx = t; idx < kNT*24; idx += 512) {
    int n = idx / 24, p = idx % 24;
    const unsigned short* base = qkv + ((size_t)(b*kNT + n))*1152 + hh*kHD + 2*p;
    float q0 = bf2f(base[0]),   q1 = bf2f(base[1]);
    float k0 = bf2f(base[384]), k1 = bf2f(base[385]);
    float v0 = bf2f(base[768]), v1 = bf2f(base[769]);
    float cg = gcs[p], sg = gss[p];
    float qr = q0*cg - q1*sg, qi = q0*sg + q1*cg;
    float kr = k0*cg - k1*sg, ki = k0*sg + k1*cg;
    if (n > 0) {
      size_t pi = ((size_t)b*kG + (n-1))*24 + p;
      float pc = pcs[pi], pv = psn[pi];
      float tq = qr*pc - qi*pv; qi = qr*pv + qi*pc; qr = tq;
      float tk = kr*pc - ki*pv; ki = kr*pv + ki*pc; kr = tk;
    }
    qs[n][2*p] = qr; qs[n][2*p+1] = qi;
    ks[n][2*p] = kr; ks[n][2*p+1] = ki;
    vls[n][2*p] = v0; vls[n][2*p+1] = v1;
  }
  __syncthreads();
  const int lane = t & 63, w = t >> 6;
  for (int r = w; r < kNT; r += 8) {
    float4 q[12];
    #pragma unroll
    for (int d = 0; d < 12; ++d) q[d] = *(const float4*)(&qs[r][d*4]);
    float sv[3];
    float mx = -3.0e38f;
    #pragma unroll
    for (int ji = 0; ji < 3; ++ji) {
      int j = ji*64 + lane;
      float s = -3.0e38f;
      if (j < kNT) {
        float acc = 0.f;
        #pragma unroll
        for (int d = 0; d < 12; ++d) {
          float4 kv = *(const float4*)(&ks[j][d*4]);
          acc += q[d].x*kv.x + q[d].y*kv.y + q[d].z*kv.z + q[d].w*kv.w;
        }
        s = acc * 0.14433756729740643f;
      }
      sv[ji] = s;
      mx = fmaxf(mx, s);
    }
    #pragma unroll
    for (int off = 1; off < 64; off <<= 1) mx = fmaxf(mx, __shfl_xor(mx, off));
    float sum = 0.f;
    #pragma unroll
    for (int ji = 0; ji < 3; ++ji) {
      int j = ji*64 + lane;
      if (j < kNT) { float e = expf(sv[ji] - mx); ps[w][j] = e; sum += e; }
    }
    #pragma unroll
    for (int off = 1; off < 64; off <<= 1) sum += __shfl_xor(sum, off);
    if (lane < kHD) {
      float accv = 0.f;
      for (int j4 = 0; j4 < 128; j4 += 4) {
        float4 pv = *(const float4*)(&ps[w][j4]);
        accv += pv.x*vls[j4][lane] + pv.y*vls[j4+1][lane]
              + pv.z*vls[j4+2][lane] + pv.w*vls[j4+3][lane];
      }
      accv += ps[w][128]*vls[128][lane];
      o[((size_t)(b*kNT + r))*kC + hh*kHD + lane] = f2bf(accv / sum);
    }
  }
}

// ------------------------------------------------------------- head
__global__ __launch_bounds__(256) void head_kernel(
    const float* __restrict__ xf,
    const float* __restrict__ hw1, const float* __restrict__ hb1,
    const float* __restrict__ hg1, const float* __restrict__ hbe1,
    const float* __restrict__ hw2, const float* __restrict__ hb2,
    const float* __restrict__ hg2, const float* __restrict__ hbe2,
    const float* __restrict__ hw3, const float* __restrict__ hb3,
    float* __restrict__ out)
{
  __shared__ float f[768];
  __shared__ float h1[256], h2[256];
  const int t = threadIdx.x;
  const int b = blockIdx.x;
  const float* xb = xf + (size_t)b*kNT*kC;
  for (int c = t; c < kC; c += 256) {
    f[c] = xb[c];
    float mx = -3.0e38f;
    for (int n = 1; n < kNT; ++n) mx = fmaxf(mx, xb[(size_t)n*kC + c]);
    f[kC + c] = mx;
  }
  __syncthreads();
  {
    float acc = hb1[t];
    for (int k = 0; k < 768; k += 4) {
      float4 wv = *(const float4*)(hw1 + (size_t)t*768 + k);
      float4 fv = *(const float4*)(&f[k]);
      acc += fv.x*wv.x + fv.y*wv.y + fv.z*wv.z + fv.w*wv.w;
    }
    h1[t] = fmaxf(acc*hg1[t] + hbe1[t], 0.0f);
  }
  __syncthreads();
  {
    float acc = hb2[t];
    for (int k = 0; k < 256; k += 4) {
      float4 wv = *(const float4*)(hw2 + (size_t)t*256 + k);
      float4 fv = *(const float4*)(&h1[k]);
      acc += fv.x*wv.x + fv.y*wv.y + fv.z*wv.z + fv.w*wv.w;
    }
    h2[t] = fmaxf(acc*hg2[t] + hbe2[t], 0.0f);
  }
  __syncthreads();
  if (t < 40) {
    float acc = hb3[t];
    for (int k = 0; k < 256; k += 4) {
      float4 wv = *(const float4*)(hw3 + (size_t)t*256 + k);
      float4 fv = *(const float4*)(&h2[k]);
      acc += fv.x*wv.x + fv.y*wv.y + fv.z*wv.z + fv.w*wv.w;
    }
    out[(size_t)b*40 + t] = acc;
  }
}

// ------------------------------------------------------------- launch
extern "C" void kernel_launch(void* const* d_in, const int* in_sizes, int n_in,
                              void* d_out, int out_size, void* d_ws, size_t ws_size,
                              hipStream_t stream) {
  const float* pts     = (const float*)d_in[0];
  const float* enc_w1  = (const float*)d_in[1];
  const float* enc_b1  = (const float*)d_in[2];
  const float* enc_g1  = (const float*)d_in[3];
  const float* enc_be1 = (const float*)d_in[4];
  const float* enc_w2  = (const float*)d_in[5];
  const float* enc_b2  = (const float*)d_in[6];
  const float* enc_w3  = (const float*)d_in[7];
  const float* enc_b3  = (const float*)d_in[8];
  const float* enc_g2  = (const float*)d_in[9];
  const float* enc_be2 = (const float*)d_in[10];
  const float* enc_w4  = (const float*)d_in[11];
  const float* enc_b4  = (const float*)d_in[12];
  const float* cls_tok = (const float*)d_in[13];
  const float* cls_pos = (const float*)d_in[14];
  const float* ln1_g   = (const float*)d_in[15];
  const float* ln1_b   = (const float*)d_in[16];
  const float* qkv_w   = (const float*)d_in[17];
  const float* givens  = (const float*)d_in[18];
  const float* proj_w  = (const float*)d_in[19];
  const float* proj_b  = (const float*)d_in[20];
  const float* ln2_g   = (const float*)d_in[21];
  const float* ln2_b   = (const float*)d_in[22];
  const float* fc1_w   = (const float*)d_in[23];
  const float* fc1_b   = (const float*)d_in[24];
  const float* fc2_w   = (const float*)d_in[25];
  const float* fc2_b   = (const float*)d_in[26];
  const float* norm_g  = (const float*)d_in[27];
  const float* norm_b  = (const float*)d_in[28];
  const float* hw1     = (const float*)d_in[29];
  const float* hb1     = (const float*)d_in[30];
  const float* hg1     = (const float*)d_in[31];
  const float* hbe1    = (const float*)d_in[32];
  const float* hw2     = (const float*)d_in[33];
  const float* hb2     = (const float*)d_in[34];
  const float* hg2     = (const float*)d_in[35];
  const float* hbe2    = (const float*)d_in[36];
  const float* hw3     = (const float*)d_in[37];
  const float* hb3     = (const float*)d_in[38];

  char* wsb = (char*)d_ws;
  size_t off = 0;
  float* center = (float*)(wsb + off); off += (size_t)kB*kG*3*4;        // 48KB
  float* pcs    = (float*)(wsb + off); off += (size_t)kB*kG*24*4;       // 384KB
  float* psn    = (float*)(wsb + off); off += (size_t)kB*kG*24*4;       // 384KB
  float* neigh  = (float*)(wsb + off); off += (size_t)kB*kG*kM*3*4;     // 1.5MB
  float* xbuf   = (float*)(wsb + off); off += (size_t)kRows*kC*4;       // 6.05MB
  char* scratch = wsb + off;
  // encoder view of scratch (per chunk)
  unsigned short* f1c   = (unsigned short*)(scratch);
  unsigned short* f2c   = (unsigned short*)(scratch + 4194304);
  unsigned short* fgc   = (unsigned short*)(scratch + 4194304 + 8388608);
  float*          basec = (float*)(scratch + 4194304 + 8388608 + 262144);
  unsigned short* f3c   = (unsigned short*)(scratch + 4194304 + 8388608 + 262144 + 1048576);
  // transformer view of scratch (aliased)
  unsigned short* hbuf   = (unsigned short*)(scratch);
  unsigned short* qkvb   = (unsigned short*)(scratch + 3170304);
  unsigned short* attnob = (unsigned short*)(scratch + 3170304 + 9510912);
  unsigned short* mlpb   = (unsigned short*)(scratch + 3170304 + 9510912 + 3170304);
  float*          flnb   = (float*)(scratch + 3170304);  // aliases qkvb (post-loop)

  fps_kernel<<<kB, 1024, 0, stream>>>(pts, center);
  rope_kernel<<<(kB*kG*24 + 255)/256, 256, 0, stream>>>(center, pcs, psn);
  knn_kernel<<<kB*kG, 256, 0, stream>>>(pts, center, neigh);

  // ---- encoder: 8 chunks of 512 groups (16384 rows) ----
  for (int c = 0; c < 8; ++c) {
    const float* nc = neigh + (size_t)c*kRC*3;
    enc1_kernel<<<kRC/2, 256, 0, stream>>>(nc, enc_w1, enc_b1, enc_g1, enc_be1, f1c);
    mgemm_kernel<1><<<dim3(kRC/128, 2), 256, 0, stream>>>(
        f1c, 128, enc_w2, 128, f2c, enc_b2, nullptr, nullptr, nullptr,
        kRC, 256, 128, nullptr, 0);
    pool2_kernel<<<kGC, 256, 0, stream>>>(f2c, fgc);
    mgemm_kernel<2><<<dim3(kGC/128, 4), 256, 0, stream>>>(
        fgc, 256, enc_w3, 512, basec, enc_b3, nullptr, nullptr, nullptr,
        kGC, 512, 256, nullptr, 0);
    mgemm_kernel<3><<<dim3(kRC/128, 4), 256, 0, stream>>>(
        f2c, 256, enc_w3 + 256, 512, f3c, nullptr, basec, enc_g2, enc_be2,
        kRC, 512, 256, nullptr, 0);
    mgemm_kernel<4><<<dim3(kRC/128, 3), 256, 0, stream>>>(
        f3c, 512, enc_w4, 512, nullptr, enc_b4, nullptr, nullptr, nullptr,
        kRC, 384, 512, xbuf, c*kGC);
  }
  cls_kernel<<<(kB*kC + 255)/256, 256, 0, stream>>>(cls_tok, cls_pos, xbuf);

  const int lnGrid = kRows/4;
  for (int l = 0; l < 12; ++l) {
    ln_kernel<1><<<lnGrid, 256, 0, stream>>>(xbuf, hbuf, ln1_g + l*kC, ln1_b + l*kC);
    mgemm_kernel<0><<<dim3(33, 9), 256, 0, stream>>>(
        hbuf, kC, qkv_w + (size_t)l*1152*kC, kC, qkvb, nullptr, nullptr, nullptr, nullptr,
        kRows, 1152, kC, nullptr, 0);
    attn_kernel<<<kB*kH, 512, 0, stream>>>(qkvb, pcs, psn, givens + (size_t)l*kH*24, attnob);
    mgemm_kernel<5><<<dim3(33, 3), 256, 0, stream>>>(
        attnob, kC, proj_w + (size_t)l*kC*kC, kC, xbuf, proj_b + l*kC, xbuf, nullptr, nullptr,
        kRows, kC, kC, nullptr, 0);
    ln_kernel<1><<<lnGrid, 256, 0, stream>>>(xbuf, hbuf, ln2_g + l*kC, ln2_b + l*kC);
    mgemm_kernel<6><<<dim3(33, 12), 256, 0, stream>>>(
        hbuf, kC, fc1_w + (size_t)l*kMLP*kC, kC, mlpb, fc1_b + l*kMLP, nullptr, nullptr, nullptr,
        kRows, kMLP, kC, nullptr, 0);
    mgemm_kernel<5><<<dim3(33, 3), 256, 0, stream>>>(
        mlpb, kMLP, fc2_w + (size_t)l*kC*kMLP, kMLP, xbuf, fc2_b + l*kC, xbuf, nullptr, nullptr,
        kRows, kC, kMLP, nullptr, 0);
  }
  ln_kernel<0><<<lnGrid, 256, 0, stream>>>(xbuf, flnb, norm_g, norm_b);
  head_kernel<<<kB, 256, 0, stream>>>(flnb,
      hw1, hb1, hg1, hbe1, hw2, hb2, hg2, hbe2, hw3, hb3, (float*)d_out);
}

// Round 3
// 2595.059 us; speedup vs baseline: 3.8723x; 1.2935x over previous
//
#include <hip/hip_runtime.h>
#include <math.h>

// Problem constants
constexpr int kB   = 32;     // batch
constexpr int kN   = 2048;   // raw points
constexpr int kG   = 128;    // groups (FPS centers)
constexpr int kM   = 32;     // group size (KNN)
constexpr int kC   = 384;    // trans dim
constexpr int kH   = 8;      // heads
constexpr int kHD  = 48;     // head dim
constexpr int kNT  = 129;    // tokens (CLS + groups)
constexpr int kMLP = 1536;
constexpr int kRows = kB * kNT; // 4128
constexpr int kGC  = 512;       // encoder groups per chunk
constexpr int kRC  = kGC * kM;  // encoder rows per chunk = 16384

typedef __attribute__((ext_vector_type(8))) short bf16x8;
typedef __attribute__((ext_vector_type(4))) float f32x4;

__device__ __forceinline__ unsigned short f2bf(float x) {
  unsigned u = __float_as_uint(x);
  unsigned r = (u + 0x7fffu + ((u >> 16) & 1u)) >> 16;
  return (unsigned short)r;
}
__device__ __forceinline__ float bf2f(unsigned short u) {
  return __uint_as_float(((unsigned)u) << 16);
}

// ---------------------------------------------------------------- FPS
// Single wave per batch; 32 points/lane in registers (blocked ownership so
// first-index tie-breaks reduce left-to-right). LDS holds the point cloud
// only for the uniform-address broadcast of the selected point (no barriers
// needed after init: LDS is read-only and the argmax result is butterfly-
// reduced so every lane agrees).
__global__ __launch_bounds__(64) void fps_kernel(
    const float* __restrict__ pts, float* __restrict__ center)
{
  #pragma clang fp contract(off)
  __shared__ float sx[kN], sy[kN], sz[kN];
  const int b = blockIdx.x, lane = threadIdx.x;
  const float* P = pts + (size_t)b * kN * 3;
  float rx[32], ry[32], rz[32], rd[32];
  const int base = lane * 32;
  #pragma unroll
  for (int j = 0; j < 32; ++j) {
    int i = base + j;
    float x = P[3*i], y = P[3*i+1], z = P[3*i+2];
    rx[j] = x; ry[j] = y; rz[j] = z; rd[j] = 1e10f;
    sx[i] = x; sy[i] = y; sz[i] = z;
  }
  __syncthreads();
  int last = 0;
  float* cb = center + (size_t)b * kG * 3;
  for (int it = 0; it < kG; ++it) {
    float lx = sx[last], ly = sy[last], lz = sz[last];  // uniform broadcast
    if (lane == 0) { cb[3*it] = lx; cb[3*it+1] = ly; cb[3*it+2] = lz; }
    float bestv = -1.0f; int besti = kN;
    #pragma unroll
    for (int j = 0; j < 32; ++j) {
      float dx = rx[j]-lx, dy = ry[j]-ly, dz = rz[j]-lz;
      float d = (dx*dx + dy*dy) + dz*dz;
      float nd = fminf(rd[j], d);
      rd[j] = nd;
      if (nd > bestv) { bestv = nd; besti = base + j; }
    }
    #pragma unroll
    for (int off = 1; off < 64; off <<= 1) {
      float vv = __shfl_xor(bestv, off);
      int   ii = __shfl_xor(besti, off);
      if (vv > bestv || (vv == bestv && ii < besti)) { bestv = vv; besti = ii; }
    }
    last = besti;
  }
}

// ------------------------------------------------------- RoPE cos/sin table
__global__ void rope_kernel(const float* __restrict__ center,
                            float* __restrict__ pcs, float* __restrict__ psn)
{
  int idx = blockIdx.x*256 + threadIdx.x;
  if (idx >= kB*kG*24) return;
  int p  = idx % 24;
  int bg = idx / 24;
  int axis = p >> 3, j = p & 7;
  float e  = (float)(2*j) / 16.0f;
  float fr = 1.0f / powf(100.0f, e);
  float ang = center[(size_t)bg*3 + axis] * fr;
  pcs[idx] = cosf(ang);
  psn[idx] = sinf(ang);
}

// ---------------------------------------------------------------- KNN
__global__ __launch_bounds__(256) void knn_kernel(
    const float* __restrict__ pts, const float* __restrict__ center,
    float* __restrict__ neigh)
{
  #pragma clang fp contract(off)
  __shared__ float d2s[kN];
  __shared__ float rv[4];
  __shared__ int   ri[4];
  const int t = threadIdx.x;
  const int bg = blockIdx.x;
  const int b = bg >> 7;
  const float* P = pts + (size_t)b * kN * 3;
  const float cx = center[(size_t)bg*3+0];
  const float cy = center[(size_t)bg*3+1];
  const float cz = center[(size_t)bg*3+2];
  for (int i = t; i < kN; i += 256) {
    float dx = cx - P[3*i], dy = cy - P[3*i+1], dz = cz - P[3*i+2];
    d2s[i] = (dx*dx + dy*dy) + dz*dz;
  }
  __syncthreads();
  for (int m = 0; m < kM; ++m) {
    float bestv = 3.0e38f; int besti = kN;
    for (int i = t; i < kN; i += 256) {
      float v = d2s[i];
      if (v < bestv || (v == bestv && i < besti)) { bestv = v; besti = i; }
    }
    #pragma unroll
    for (int off = 32; off > 0; off >>= 1) {
      float vv = __shfl_down(bestv, off);
      int   ii = __shfl_down(besti, off);
      if (vv < bestv || (vv == bestv && ii < besti)) { bestv = vv; besti = ii; }
    }
    if ((t & 63) == 0) { rv[t>>6] = bestv; ri[t>>6] = besti; }
    __syncthreads();
    if (t == 0) {
      float bv = rv[0]; int bi = ri[0];
      for (int w = 1; w < 4; ++w)
        if (rv[w] < bv || (rv[w] == bv && ri[w] < bi)) { bv = rv[w]; bi = ri[w]; }
      d2s[bi] = 3.0e38f;
      float* o = neigh + ((size_t)bg*kM + m)*3;
      o[0] = P[3*bi+0] - cx; o[1] = P[3*bi+1] - cy; o[2] = P[3*bi+2] - cz;
    }
    __syncthreads();
  }
}

// ------------------------------------------------- encoder layer1 (3->128)
__global__ __launch_bounds__(256) void enc1_kernel(
    const float* __restrict__ neighC,
    const float* __restrict__ w1, const float* __restrict__ b1,
    const float* __restrict__ g1, const float* __restrict__ be1,
    unsigned short* __restrict__ f1c)
{
  const int t = threadIdx.x;
  const int r = blockIdx.x*2 + (t >> 7);
  const int c = t & 127;
  const float* nr = neighC + (size_t)r*3;
  float x0 = nr[0], x1 = nr[1], x2 = nr[2];
  float s = x0*w1[3*c] + x1*w1[3*c+1] + x2*w1[3*c+2] + b1[c];
  float v = fmaxf(s*g1[c] + be1[c], 0.0f);
  f1c[(size_t)r*128 + c] = f2bf(v);
}

// ------------------------------------------------- encoder fg pool (layer2 max)
__global__ __launch_bounds__(256) void pool2_kernel(
    const unsigned short* __restrict__ f2c, unsigned short* __restrict__ fgc)
{
  const int g = blockIdx.x, c = threadIdx.x;
  float mx = -3.0e38f;
  #pragma unroll 8
  for (int m = 0; m < kM; ++m)
    mx = fmaxf(mx, bf2f(f2c[((size_t)g*kM + m)*256 + c]));
  fgc[(size_t)g*256 + c] = f2bf(mx);
}

// ------------------------------------------------------------- MFMA GEMM
// Out[M,N] (+epilogue) = A[M,K](bf16,lda) @ B[N,K](fp32,ldb)^T
// Block tile BMxBN with BM=FM*32, BN=FN*32; BK=64; 256 thr = 4 waves (2x2),
// each wave (FM*16)x(FN*16) via FMxFN 16x16 fragments. 64x64 tile -> 18.4KB
// LDS -> 8 blocks/CU; grids 4-6x larger than the old 128x128 version.
// EPI: 0 bf16 plain | 1 bf16 +bias | 2 f32 +bias | 3 bf16 relu((v+base[r>>5])*g+be)
//      4 fused 32-row max-pool (+bias) -> tokens (FM==2) | 5 f32 res+v+bias | 6 bf16 gelu(v+bias)
template <int EPI, int FM, int FN>
__global__ __launch_bounds__(256) void mgemm_kernel(
    const unsigned short* __restrict__ A, int lda,
    const float* __restrict__ B, int ldb,
    void* __restrict__ Cv,
    const float* __restrict__ bias,
    const float* __restrict__ aux,       // res (EPI5) or base (EPI3)
    const float* __restrict__ gsc, const float* __restrict__ bsc,  // EPI3
    int Mm, int Nn, int Kk,
    float* __restrict__ poolOut, int poolG0)
{
  constexpr int BM = FM*32, BN = FN*32;
  __shared__ unsigned short As[BM][72];
  __shared__ unsigned short Bs[BN][72];
  const int t = threadIdx.x;
  const int m0 = blockIdx.x * BM;
  const int n0 = blockIdx.y * BN;
  const int w = t >> 6, lane = t & 63;
  const int wm = w >> 1, wn = w & 1;
  const int lr = lane & 15;
  const int lk = (lane >> 4) * 8;
  const int srow = t >> 3;          // 0..31
  const int skseg = (t & 7) * 8;    // 0..56
  f32x4 acc[FM][FN] = {};
  for (int k0 = 0; k0 < Kk; k0 += 64) {
    #pragma unroll
    for (int p = 0; p < BM/32; ++p) {
      int r = p*32 + srow;
      int gr = m0 + r;
      bf16x8 av = {};
      if (gr < Mm) av = *(const bf16x8*)(A + (size_t)gr*lda + k0 + skseg);
      *(bf16x8*)(&As[r][skseg]) = av;
    }
    #pragma unroll
    for (int p = 0; p < BN/32; ++p) {
      int r = p*32 + srow;
      const float* bp = B + (size_t)(n0 + r)*ldb + k0 + skseg;
      float4 b0 = *(const float4*)(bp);
      float4 b1 = *(const float4*)(bp + 4);
      bf16x8 bv;
      bv[0] = (short)f2bf(b0.x); bv[1] = (short)f2bf(b0.y);
      bv[2] = (short)f2bf(b0.z); bv[3] = (short)f2bf(b0.w);
      bv[4] = (short)f2bf(b1.x); bv[5] = (short)f2bf(b1.y);
      bv[6] = (short)f2bf(b1.z); bv[7] = (short)f2bf(b1.w);
      *(bf16x8*)(&Bs[r][skseg]) = bv;
    }
    __syncthreads();
    #pragma unroll
    for (int kk = 0; kk < 64; kk += 32) {
      bf16x8 af[FM], bf[FN];
      #pragma unroll
      for (int i = 0; i < FM; ++i)
        af[i] = *(const bf16x8*)(&As[wm*(FM*16) + i*16 + lr][kk + lk]);
      #pragma unroll
      for (int i = 0; i < FN; ++i)
        bf[i] = *(const bf16x8*)(&Bs[wn*(FN*16) + i*16 + lr][kk + lk]);
      #pragma unroll
      for (int i = 0; i < FM; ++i)
        #pragma unroll
        for (int j = 0; j < FN; ++j)
          acc[i][j] = __builtin_amdgcn_mfma_f32_16x16x32_bf16(af[i], bf[j], acc[i][j], 0, 0, 0);
    }
    __syncthreads();
  }

  if constexpr (EPI == 4) {
    // fused max-pool over the wave's 32-row group (FM==2, Mm%64==0)
    #pragma unroll
    for (int ni = 0; ni < FN; ++ni) {
      int cc = n0 + wn*(FN*16) + ni*16 + lr;
      float mx = -3.0e38f;
      #pragma unroll
      for (int mi = 0; mi < FM; ++mi)
        #pragma unroll
        for (int j = 0; j < 4; ++j)
          mx = fmaxf(mx, acc[mi][ni][j]);
      mx = fmaxf(mx, __shfl_xor(mx, 16));
      mx = fmaxf(mx, __shfl_xor(mx, 32));
      if ((lane >> 4) == 0) {
        int ggl = poolG0 + (m0 >> 5) + wm;
        int b = ggl >> 7, g = ggl & 127;
        poolOut[((size_t)b*kNT + 1 + g)*kC + cc] = mx + bias[cc];
      }
    }
    return;
  }

  #pragma unroll
  for (int mi = 0; mi < FM; ++mi) {
    #pragma unroll
    for (int j = 0; j < 4; ++j) {
      int r = m0 + wm*(FM*16) + mi*16 + (lane >> 4)*4 + j;
      if (r < Mm) {
        #pragma unroll
        for (int ni = 0; ni < FN; ++ni) {
          int cc = n0 + wn*(FN*16) + ni*16 + lr;
          float v = acc[mi][ni][j];
          size_t o = (size_t)r*Nn + cc;
          if constexpr (EPI == 0) {
            ((unsigned short*)Cv)[o] = f2bf(v);
          } else if constexpr (EPI == 1) {
            ((unsigned short*)Cv)[o] = f2bf(v + bias[cc]);
          } else if constexpr (EPI == 2) {
            ((float*)Cv)[o] = v + bias[cc];
          } else if constexpr (EPI == 3) {
            float u = (v + aux[(size_t)(r >> 5)*Nn + cc])*gsc[cc] + bsc[cc];
            ((unsigned short*)Cv)[o] = f2bf(fmaxf(u, 0.0f));
          } else if constexpr (EPI == 5) {
            ((float*)Cv)[o] = aux[o] + v + bias[cc];
          } else {
            float u = v + bias[cc];
            ((unsigned short*)Cv)[o] = f2bf(0.5f*u*(1.0f + erff(u*0.70710678118654752440f)));
          }
        }
      }
    }
  }
}

// ----------------------------------------------------------- CLS token init
__global__ void cls_kernel(const float* __restrict__ ct, const float* __restrict__ cp,
                           float* __restrict__ x)
{
  int idx = blockIdx.x*256 + threadIdx.x;
  if (idx >= kB*kC) return;
  int b = idx / kC, c = idx % kC;
  x[(size_t)b*kNT*kC + c] = ct[c] + cp[c];
}

// ------------------------------------------------------------- LayerNorm
template <int OUTBF>
__global__ __launch_bounds__(256) void ln_kernel(
    const float* __restrict__ in, void* __restrict__ outv,
    const float* __restrict__ g, const float* __restrict__ bb)
{
  const int t = threadIdx.x;
  const int lane = t & 63;
  const int row = blockIdx.x*4 + (t >> 6);
  const float* p = in + (size_t)row*kC;
  float v[6];
  #pragma unroll
  for (int k = 0; k < 6; ++k) v[k] = p[k*64 + lane];
  float s = 0.f;
  #pragma unroll
  for (int k = 0; k < 6; ++k) s += v[k];
  #pragma unroll
  for (int off = 1; off < 64; off <<= 1) s += __shfl_xor(s, off);
  float mean = s / 384.0f;
  float vs = 0.f;
  #pragma unroll
  for (int k = 0; k < 6; ++k) { float d = v[k]-mean; vs += d*d; }
  #pragma unroll
  for (int off = 1; off < 64; off <<= 1) vs += __shfl_xor(vs, off);
  float r = rsqrtf(vs / 384.0f + 1e-5f);
  #pragma unroll
  for (int k = 0; k < 6; ++k) {
    int c = k*64 + lane;
    float o = (v[k]-mean)*r*g[c] + bb[c];
    if constexpr (OUTBF) ((unsigned short*)outv)[(size_t)row*kC + c] = f2bf(o);
    else                 ((float*)outv)[(size_t)row*kC + c] = o;
  }
}

// ------------------------------------------------------------- attention
__global__ __launch_bounds__(512) void attn_kernel(
    const unsigned short* __restrict__ qkv, const float* __restrict__ pcs,
    const float* __restrict__ psn, const float* __restrict__ gth,
    unsigned short* __restrict__ o)
{
  __shared__ float qs[kNT][kHD];
  __shared__ float ks[kNT][kHD];
  __shared__ float vls[kNT][kHD];
  __shared__ float gcs[24], gss[24];
  __shared__ float ps[8][132];
  const int t = threadIdx.x;
  const int bh = blockIdx.x;
  const int b = bh >> 3, hh = bh & 7;
  if (t < 24) { float th = gth[hh*24 + t]; gcs[t] = cosf(th); gss[t] = sinf(th); }
  __syncthreads();
  for (int idx = t; idx < kNT*24; idx += 512) {
    int n = idx / 24, p = idx % 24;
    const unsigned short* base = qkv + ((size_t)(b*kNT + n))*1152 + hh*kHD + 2*p;
    float q0 = bf2f(base[0]),   q1 = bf2f(base[1]);
    float k0 = bf2f(base[384]), k1 = bf2f(base[385]);
    float v0 = bf2f(base[768]), v1 = bf2f(base[769]);
    float cg = gcs[p], sg = gss[p];
    float qr = q0*cg - q1*sg, qi = q0*sg + q1*cg;
    float kr = k0*cg - k1*sg, ki = k0*sg + k1*cg;
    if (n > 0) {
      size_t pi = ((size_t)b*kG + (n-1))*24 + p;
      float pc = pcs[pi], pv = psn[pi];
      float tq = qr*pc - qi*pv; qi = qr*pv + qi*pc; qr = tq;
      float tk = kr*pc - ki*pv; ki = kr*pv + ki*pc; kr = tk;
    }
    qs[n][2*p] = qr; qs[n][2*p+1] = qi;
    ks[n][2*p] = kr; ks[n][2*p+1] = ki;
    vls[n][2*p] = v0; vls[n][2*p+1] = v1;
  }
  __syncthreads();
  const int lane = t & 63, w = t >> 6;
  for (int r = w; r < kNT; r += 8) {
    float4 q[12];
    #pragma unroll
    for (int d = 0; d < 12; ++d) q[d] = *(const float4*)(&qs[r][d*4]);
    float sv[3];
    float mx = -3.0e38f;
    #pragma unroll
    for (int ji = 0; ji < 3; ++ji) {
      int j = ji*64 + lane;
      float s = -3.0e38f;
      if (j < kNT) {
        float a0 = 0.f, a1 = 0.f;   // 2-way ILP on the dot chain
        #pragma unroll
        for (int d = 0; d < 12; d += 2) {
          float4 k0v = *(const float4*)(&ks[j][d*4]);
          float4 k1v = *(const float4*)(&ks[j][d*4+4]);
          a0 += q[d].x*k0v.x + q[d].y*k0v.y + q[d].z*k0v.z + q[d].w*k0v.w;
          a1 += q[d+1].x*k1v.x + q[d+1].y*k1v.y + q[d+1].z*k1v.z + q[d+1].w*k1v.w;
        }
        s = (a0 + a1) * 0.14433756729740643f;
      }
      sv[ji] = s;
      mx = fmaxf(mx, s);
    }
    #pragma unroll
    for (int off = 1; off < 64; off <<= 1) mx = fmaxf(mx, __shfl_xor(mx, off));
    float sum = 0.f;
    #pragma unroll
    for (int ji = 0; ji < 3; ++ji) {
      int j = ji*64 + lane;
      if (j < kNT) { float e = expf(sv[ji] - mx); ps[w][j] = e; sum += e; }
    }
    #pragma unroll
    for (int off = 1; off < 64; off <<= 1) sum += __shfl_xor(sum, off);
    if (lane < kHD) {
      // 4 independent accumulator chains (PV was a 512-dep-FMA chain)
      float ac0 = 0.f, ac1 = 0.f, ac2 = 0.f, ac3 = 0.f;
      for (int j4 = 0; j4 < 128; j4 += 16) {
        float4 p0 = *(const float4*)(&ps[w][j4]);
        float4 p1 = *(const float4*)(&ps[w][j4+4]);
        float4 p2 = *(const float4*)(&ps[w][j4+8]);
        float4 p3 = *(const float4*)(&ps[w][j4+12]);
        ac0 += p0.x*vls[j4+0][lane] + p0.y*vls[j4+1][lane]
             + p0.z*vls[j4+2][lane] + p0.w*vls[j4+3][lane];
        ac1 += p1.x*vls[j4+4][lane] + p1.y*vls[j4+5][lane]
             + p1.z*vls[j4+6][lane] + p1.w*vls[j4+7][lane];
        ac2 += p2.x*vls[j4+8][lane] + p2.y*vls[j4+9][lane]
             + p2.z*vls[j4+10][lane] + p2.w*vls[j4+11][lane];
        ac3 += p3.x*vls[j4+12][lane] + p3.y*vls[j4+13][lane]
             + p3.z*vls[j4+14][lane] + p3.w*vls[j4+15][lane];
      }
      float accv = ((ac0 + ac1) + (ac2 + ac3)) + ps[w][128]*vls[128][lane];
      o[((size_t)(b*kNT + r))*kC + hh*kHD + lane] = f2bf(accv / sum);
    }
  }
}

// ------------------------------------------------------------- head
__global__ __launch_bounds__(256) void head_kernel(
    const float* __restrict__ xf,
    const float* __restrict__ hw1, const float* __restrict__ hb1,
    const float* __restrict__ hg1, const float* __restrict__ hbe1,
    const float* __restrict__ hw2, const float* __restrict__ hb2,
    const float* __restrict__ hg2, const float* __restrict__ hbe2,
    const float* __restrict__ hw3, const float* __restrict__ hb3,
    float* __restrict__ out)
{
  __shared__ float f[768];
  __shared__ float h1[256], h2[256];
  const int t = threadIdx.x;
  const int b = blockIdx.x;
  const float* xb = xf + (size_t)b*kNT*kC;
  for (int c = t; c < kC; c += 256) {
    f[c] = xb[c];
    float mx = -3.0e38f;
    for (int n = 1; n < kNT; ++n) mx = fmaxf(mx, xb[(size_t)n*kC + c]);
    f[kC + c] = mx;
  }
  __syncthreads();
  {
    float acc = hb1[t];
    for (int k = 0; k < 768; k += 4) {
      float4 wv = *(const float4*)(hw1 + (size_t)t*768 + k);
      float4 fv = *(const float4*)(&f[k]);
      acc += fv.x*wv.x + fv.y*wv.y + fv.z*wv.z + fv.w*wv.w;
    }
    h1[t] = fmaxf(acc*hg1[t] + hbe1[t], 0.0f);
  }
  __syncthreads();
  {
    float acc = hb2[t];
    for (int k = 0; k < 256; k += 4) {
      float4 wv = *(const float4*)(hw2 + (size_t)t*256 + k);
      float4 fv = *(const float4*)(&h1[k]);
      acc += fv.x*wv.x + fv.y*wv.y + fv.z*wv.z + fv.w*wv.w;
    }
    h2[t] = fmaxf(acc*hg2[t] + hbe2[t], 0.0f);
  }
  __syncthreads();
  if (t < 40) {
    float acc = hb3[t];
    for (int k = 0; k < 256; k += 4) {
      float4 wv = *(const float4*)(hw3 + (size_t)t*256 + k);
      float4 fv = *(const float4*)(&h2[k]);
      acc += fv.x*wv.x + fv.y*wv.y + fv.z*wv.z + fv.w*wv.w;
    }
    out[(size_t)b*40 + t] = acc;
  }
}

// ------------------------------------------------------------- launch
extern "C" void kernel_launch(void* const* d_in, const int* in_sizes, int n_in,
                              void* d_out, int out_size, void* d_ws, size_t ws_size,
                              hipStream_t stream) {
  const float* pts     = (const float*)d_in[0];
  const float* enc_w1  = (const float*)d_in[1];
  const float* enc_b1  = (const float*)d_in[2];
  const float* enc_g1  = (const float*)d_in[3];
  const float* enc_be1 = (const float*)d_in[4];
  const float* enc_w2  = (const float*)d_in[5];
  const float* enc_b2  = (const float*)d_in[6];
  const float* enc_w3  = (const float*)d_in[7];
  const float* enc_b3  = (const float*)d_in[8];
  const float* enc_g2  = (const float*)d_in[9];
  const float* enc_be2 = (const float*)d_in[10];
  const float* enc_w4  = (const float*)d_in[11];
  const float* enc_b4  = (const float*)d_in[12];
  const float* cls_tok = (const float*)d_in[13];
  const float* cls_pos = (const float*)d_in[14];
  const float* ln1_g   = (const float*)d_in[15];
  const float* ln1_b   = (const float*)d_in[16];
  const float* qkv_w   = (const float*)d_in[17];
  const float* givens  = (const float*)d_in[18];
  const float* proj_w  = (const float*)d_in[19];
  const float* proj_b  = (const float*)d_in[20];
  const float* ln2_g   = (const float*)d_in[21];
  const float* ln2_b   = (const float*)d_in[22];
  const float* fc1_w   = (const float*)d_in[23];
  const float* fc1_b   = (const float*)d_in[24];
  const float* fc2_w   = (const float*)d_in[25];
  const float* fc2_b   = (const float*)d_in[26];
  const float* norm_g  = (const float*)d_in[27];
  const float* norm_b  = (const float*)d_in[28];
  const float* hw1     = (const float*)d_in[29];
  const float* hb1     = (const float*)d_in[30];
  const float* hg1     = (const float*)d_in[31];
  const float* hbe1    = (const float*)d_in[32];
  const float* hw2     = (const float*)d_in[33];
  const float* hb2     = (const float*)d_in[34];
  const float* hg2     = (const float*)d_in[35];
  const float* hbe2    = (const float*)d_in[36];
  const float* hw3     = (const float*)d_in[37];
  const float* hb3     = (const float*)d_in[38];

  char* wsb = (char*)d_ws;
  size_t off = 0;
  float* center = (float*)(wsb + off); off += (size_t)kB*kG*3*4;
  float* pcs    = (float*)(wsb + off); off += (size_t)kB*kG*24*4;
  float* psn    = (float*)(wsb + off); off += (size_t)kB*kG*24*4;
  float* neigh  = (float*)(wsb + off); off += (size_t)kB*kG*kM*3*4;
  float* xbuf   = (float*)(wsb + off); off += (size_t)kRows*kC*4;
  char* scratch = wsb + off;
  // encoder view of scratch (per chunk)
  unsigned short* f1c   = (unsigned short*)(scratch);
  unsigned short* f2c   = (unsigned short*)(scratch + 4194304);
  unsigned short* fgc   = (unsigned short*)(scratch + 4194304 + 8388608);
  float*          basec = (float*)(scratch + 4194304 + 8388608 + 262144);
  unsigned short* f3c   = (unsigned short*)(scratch + 4194304 + 8388608 + 262144 + 1048576);
  // transformer view of scratch (aliased)
  unsigned short* hbuf   = (unsigned short*)(scratch);
  unsigned short* qkvb   = (unsigned short*)(scratch + 3170304);
  unsigned short* attnob = (unsigned short*)(scratch + 3170304 + 9510912);
  unsigned short* mlpb   = (unsigned short*)(scratch + 3170304 + 9510912 + 3170304);
  float*          flnb   = (float*)(scratch + 3170304);  // aliases qkvb (post-loop)

  fps_kernel<<<kB, 64, 0, stream>>>(pts, center);
  rope_kernel<<<(kB*kG*24 + 255)/256, 256, 0, stream>>>(center, pcs, psn);
  knn_kernel<<<kB*kG, 256, 0, stream>>>(pts, center, neigh);

  // ---- encoder: 8 chunks of 512 groups (16384 rows) ----
  for (int c = 0; c < 8; ++c) {
    const float* nc = neigh + (size_t)c*kRC*3;
    enc1_kernel<<<kRC/2, 256, 0, stream>>>(nc, enc_w1, enc_b1, enc_g1, enc_be1, f1c);
    mgemm_kernel<1,2,2><<<dim3(kRC/64, 4), 256, 0, stream>>>(
        f1c, 128, enc_w2, 128, f2c, enc_b2, nullptr, nullptr, nullptr,
        kRC, 256, 128, nullptr, 0);
    pool2_kernel<<<kGC, 256, 0, stream>>>(f2c, fgc);
    mgemm_kernel<2,2,2><<<dim3(kGC/64, 8), 256, 0, stream>>>(
        fgc, 256, enc_w3, 512, basec, enc_b3, nullptr, nullptr, nullptr,
        kGC, 512, 256, nullptr, 0);
    mgemm_kernel<3,2,2><<<dim3(kRC/64, 8), 256, 0, stream>>>(
        f2c, 256, enc_w3 + 256, 512, f3c, nullptr, basec, enc_g2, enc_be2,
        kRC, 512, 256, nullptr, 0);
    mgemm_kernel<4,2,2><<<dim3(kRC/64, 6), 256, 0, stream>>>(
        f3c, 512, enc_w4, 512, nullptr, enc_b4, nullptr, nullptr, nullptr,
        kRC, 384, 512, xbuf, c*kGC);
  }
  cls_kernel<<<(kB*kC + 255)/256, 256, 0, stream>>>(cls_tok, cls_pos, xbuf);

  const int lnGrid = kRows/4;
  for (int l = 0; l < 12; ++l) {
    ln_kernel<1><<<lnGrid, 256, 0, stream>>>(xbuf, hbuf, ln1_g + l*kC, ln1_b + l*kC);
    mgemm_kernel<0,2,2><<<dim3(65, 18), 256, 0, stream>>>(
        hbuf, kC, qkv_w + (size_t)l*1152*kC, kC, qkvb, nullptr, nullptr, nullptr, nullptr,
        kRows, 1152, kC, nullptr, 0);
    attn_kernel<<<kB*kH, 512, 0, stream>>>(qkvb, pcs, psn, givens + (size_t)l*kH*24, attnob);
    mgemm_kernel<5,2,2><<<dim3(65, 6), 256, 0, stream>>>(
        attnob, kC, proj_w + (size_t)l*kC*kC, kC, xbuf, proj_b + l*kC, xbuf, nullptr, nullptr,
        kRows, kC, kC, nullptr, 0);
    ln_kernel<1><<<lnGrid, 256, 0, stream>>>(xbuf, hbuf, ln2_g + l*kC, ln2_b + l*kC);
    mgemm_kernel<6,2,2><<<dim3(65, 24), 256, 0, stream>>>(
        hbuf, kC, fc1_w + (size_t)l*kMLP*kC, kC, mlpb, fc1_b + l*kMLP, nullptr, nullptr, nullptr,
        kRows, kMLP, kC, nullptr, 0);
    mgemm_kernel<5,2,2><<<dim3(65, 6), 256, 0, stream>>>(
        mlpb, kMLP, fc2_w + (size_t)l*kC*kMLP, kMLP, xbuf, fc2_b + l*kC, xbuf, nullptr, nullptr,
        kRows, kC, kMLP, nullptr, 0);
  }
  ln_kernel<0><<<lnGrid, 256, 0, stream>>>(xbuf, flnb, norm_g, norm_b);
  head_kernel<<<kB, 256, 0, stream>>>(flnb,
      hw1, hb1, hg1, hbe1, hw2, hb2, hg2, hbe2, hw3, hb3, (float*)d_out);
}

// Round 4
// 2414.504 us; speedup vs baseline: 4.1618x; 1.0748x over previous
//
#include <hip/hip_runtime.h>
#include <math.h>

// Problem constants
constexpr int kB   = 32;     // batch
constexpr int kN   = 2048;   // raw points
constexpr int kG   = 128;    // groups (FPS centers)
constexpr int kM   = 32;     // group size (KNN)
constexpr int kC   = 384;    // trans dim
constexpr int kH   = 8;      // heads
constexpr int kHD  = 48;     // head dim
constexpr int kNT  = 129;    // tokens (CLS + groups)
constexpr int kMLP = 1536;
constexpr int kRows = kB * kNT; // 4128
constexpr int kGC  = 512;       // encoder groups per chunk
constexpr int kRC  = kGC * kM;  // encoder rows per chunk = 16384

typedef __attribute__((ext_vector_type(8))) short bf16x8;
typedef __attribute__((ext_vector_type(4))) float f32x4;

__device__ __forceinline__ unsigned short f2bf(float x) {
  unsigned u = __float_as_uint(x);
  unsigned r = (u + 0x7fffu + ((u >> 16) & 1u)) >> 16;
  return (unsigned short)r;
}
__device__ __forceinline__ float bf2f(unsigned short u) {
  return __uint_as_float(((unsigned)u) << 16);
}

// ---------------------------------------------------------------- FPS
// Single wave per batch; 32 points/lane in registers.
__global__ __launch_bounds__(64) void fps_kernel(
    const float* __restrict__ pts, float* __restrict__ center)
{
  #pragma clang fp contract(off)
  __shared__ float sx[kN], sy[kN], sz[kN];
  const int b = blockIdx.x, lane = threadIdx.x;
  const float* P = pts + (size_t)b * kN * 3;
  float rx[32], ry[32], rz[32], rd[32];
  const int base = lane * 32;
  #pragma unroll
  for (int j = 0; j < 32; ++j) {
    int i = base + j;
    float x = P[3*i], y = P[3*i+1], z = P[3*i+2];
    rx[j] = x; ry[j] = y; rz[j] = z; rd[j] = 1e10f;
    sx[i] = x; sy[i] = y; sz[i] = z;
  }
  __syncthreads();
  int last = 0;
  float* cb = center + (size_t)b * kG * 3;
  for (int it = 0; it < kG; ++it) {
    float lx = sx[last], ly = sy[last], lz = sz[last];  // uniform broadcast
    if (lane == 0) { cb[3*it] = lx; cb[3*it+1] = ly; cb[3*it+2] = lz; }
    float bestv = -1.0f; int besti = kN;
    #pragma unroll
    for (int j = 0; j < 32; ++j) {
      float dx = rx[j]-lx, dy = ry[j]-ly, dz = rz[j]-lz;
      float d = (dx*dx + dy*dy) + dz*dz;
      float nd = fminf(rd[j], d);
      rd[j] = nd;
      if (nd > bestv) { bestv = nd; besti = base + j; }
    }
    #pragma unroll
    for (int off = 1; off < 64; off <<= 1) {
      float vv = __shfl_xor(bestv, off);
      int   ii = __shfl_xor(besti, off);
      if (vv > bestv || (vv == bestv && ii < besti)) { bestv = vv; besti = ii; }
    }
    last = besti;
  }
}

// ------------------------------------------------------- RoPE cos/sin table
__global__ void rope_kernel(const float* __restrict__ center,
                            float* __restrict__ pcs, float* __restrict__ psn)
{
  int idx = blockIdx.x*256 + threadIdx.x;
  if (idx >= kB*kG*24) return;
  int p  = idx % 24;
  int bg = idx / 24;
  int axis = p >> 3, j = p & 7;
  float e  = (float)(2*j) / 16.0f;
  float fr = 1.0f / powf(100.0f, e);
  float ang = center[(size_t)bg*3 + axis] * fr;
  pcs[idx] = cosf(ang);
  psn[idx] = sinf(ang);
}

// ---------------------------------------------------------------- KNN
// One wave per group (4 waves/block share one LDS copy of the batch cloud,
// swizzled i+(i>>5) so the stride-32 per-lane reads are bank-conflict-free).
// Each lane owns 32 points' distances in registers (blocked ownership ->
// ascending-j scan + butterfly (v==bestv && ii<besti) reproduces top_k's
// first-index tie-break). No barriers in the 32-iteration selection loop.
__global__ __launch_bounds__(256) void knn_kernel(
    const float* __restrict__ pts, const float* __restrict__ center,
    float* __restrict__ neigh)
{
  #pragma clang fp contract(off)
  __shared__ float sx[kN + kN/32], sy[kN + kN/32], sz[kN + kN/32];
  const int t = threadIdx.x;
  const int lane = t & 63, w = t >> 6;
  const int blk = blockIdx.x;          // 1024 blocks; 32 per batch, 4 groups each
  const int b = blk >> 5;
  const float* P = pts + (size_t)b * kN * 3;
  for (int i = t; i < kN; i += 256) {
    int ii = i + (i >> 5);
    sx[ii] = P[3*i]; sy[ii] = P[3*i+1]; sz[ii] = P[3*i+2];
  }
  __syncthreads();
  const int bg = b*kG + (blk & 31)*4 + w;
  const float cx = center[(size_t)bg*3+0];
  const float cy = center[(size_t)bg*3+1];
  const float cz = center[(size_t)bg*3+2];
  float rd[32];
  const int base = lane * 32;
  #pragma unroll
  for (int j = 0; j < 32; ++j) {
    int is = lane*33 + j;              // (base+j) + ((base+j)>>5)
    float dx = cx - sx[is], dy = cy - sy[is], dz = cz - sz[is];
    rd[j] = (dx*dx + dy*dy) + dz*dz;
  }
  float* ob = neigh + (size_t)bg * kM * 3;
  int lastWin = -1;
  for (int m = 0; m < kM; ++m) {
    float bestv = 3.0e38f; int besti = kN;
    #pragma unroll
    for (int j = 0; j < 32; ++j) {
      float v = rd[j];
      if (base + j == lastWin) v = 3.0e38f;   // remove previous winner
      rd[j] = v;
      if (v < bestv) { bestv = v; besti = base + j; }
    }
    #pragma unroll
    for (int off = 1; off < 64; off <<= 1) {
      float vv = __shfl_xor(bestv, off);
      int   i2 = __shfl_xor(besti, off);
      if (vv < bestv || (vv == bestv && i2 < besti)) { bestv = vv; besti = i2; }
    }
    lastWin = besti;
    if (lane == 0) {
      int is = besti + (besti >> 5);          // uniform LDS read
      ob[3*m+0] = sx[is] - cx; ob[3*m+1] = sy[is] - cy; ob[3*m+2] = sz[is] - cz;
    }
  }
}

// ------------------------------------------------- weight cvt fp32 -> bf16
__global__ void wcvt_kernel(const float* __restrict__ s,
                            unsigned short* __restrict__ d, int n)
{
  int i = (blockIdx.x*256 + threadIdx.x)*8;
  if (i >= n) return;
  float4 a = *(const float4*)(s + i), b = *(const float4*)(s + i + 4);
  bf16x8 v;
  v[0]=(short)f2bf(a.x); v[1]=(short)f2bf(a.y); v[2]=(short)f2bf(a.z); v[3]=(short)f2bf(a.w);
  v[4]=(short)f2bf(b.x); v[5]=(short)f2bf(b.y); v[6]=(short)f2bf(b.z); v[7]=(short)f2bf(b.w);
  *(bf16x8*)(d + i) = v;
}

// per-layer fused conversion of qkv|proj|fc1|fc2 (1769472 elements total)
__global__ void wcvt4_kernel(const float* __restrict__ q, const float* __restrict__ p,
                             const float* __restrict__ f1, const float* __restrict__ f2,
                             unsigned short* __restrict__ d)
{
  int i = (blockIdx.x*256 + threadIdx.x)*8;   // grid sized exactly
  const float* s; int lo;
  if (i < 442368)       { s = q;  lo = i; }
  else if (i < 589824)  { s = p;  lo = i - 442368; }
  else if (i < 1179648) { s = f1; lo = i - 589824; }
  else                  { s = f2; lo = i - 1179648; }
  float4 a = *(const float4*)(s + lo), b = *(const float4*)(s + lo + 4);
  bf16x8 v;
  v[0]=(short)f2bf(a.x); v[1]=(short)f2bf(a.y); v[2]=(short)f2bf(a.z); v[3]=(short)f2bf(a.w);
  v[4]=(short)f2bf(b.x); v[5]=(short)f2bf(b.y); v[6]=(short)f2bf(b.z); v[7]=(short)f2bf(b.w);
  *(bf16x8*)(d + i) = v;
}

// ------------------------------------------------- encoder layer1 (3->128)
__global__ __launch_bounds__(256) void enc1_kernel(
    const float* __restrict__ neighC,
    const float* __restrict__ w1, const float* __restrict__ b1,
    const float* __restrict__ g1, const float* __restrict__ be1,
    unsigned short* __restrict__ f1c)
{
  const int t = threadIdx.x;
  const int r = blockIdx.x*2 + (t >> 7);
  const int c = t & 127;
  const float* nr = neighC + (size_t)r*3;
  float x0 = nr[0], x1 = nr[1], x2 = nr[2];
  float s = x0*w1[3*c] + x1*w1[3*c+1] + x2*w1[3*c+2] + b1[c];
  float v = fmaxf(s*g1[c] + be1[c], 0.0f);
  f1c[(size_t)r*128 + c] = f2bf(v);
}

// ------------------------------------------------- encoder fg pool (layer2 max)
__global__ __launch_bounds__(256) void pool2_kernel(
    const unsigned short* __restrict__ f2c, unsigned short* __restrict__ fgc)
{
  const int g = blockIdx.x, c = threadIdx.x;
  float mx = -3.0e38f;
  #pragma unroll 8
  for (int m = 0; m < kM; ++m)
    mx = fmaxf(mx, bf2f(f2c[((size_t)g*kM + m)*256 + c]));
  fgc[(size_t)g*256 + c] = f2bf(mx);
}

// ------------------------------------------------------------- MFMA GEMM
// Out[M,N] (+epilogue) = A[M,K](bf16,lda) @ B[N,K](bf16,ldb)^T
// Block tile BMxBN (BM=FM*32, BN=FN*32); BK=64; 256 thr = 4 waves (2x2).
// EPI: 0 bf16 plain | 1 bf16 +bias | 2 f32 +bias | 3 bf16 relu((v+base[r>>5])*g+be)
//      4 fused 32-row max-pool (+bias) -> tokens (FM==2) | 5 f32 res+v+bias | 6 bf16 gelu(v+bias)
template <int EPI, int FM, int FN>
__global__ __launch_bounds__(256) void mgemm_kernel(
    const unsigned short* __restrict__ A, int lda,
    const unsigned short* __restrict__ Bb, int ldb,
    void* __restrict__ Cv,
    const float* __restrict__ bias,
    const float* __restrict__ aux,       // res (EPI5) or base (EPI3)
    const float* __restrict__ gsc, const float* __restrict__ bsc,  // EPI3
    int Mm, int Nn, int Kk,
    float* __restrict__ poolOut, int poolG0)
{
  constexpr int BM = FM*32, BN = FN*32;
  __shared__ unsigned short As[BM][72];
  __shared__ unsigned short Bs[BN][72];
  const int t = threadIdx.x;
  const int m0 = blockIdx.x * BM;
  const int n0 = blockIdx.y * BN;
  const int w = t >> 6, lane = t & 63;
  const int wm = w >> 1, wn = w & 1;
  const int lr = lane & 15;
  const int lk = (lane >> 4) * 8;
  const int srow = t >> 3;          // 0..31
  const int skseg = (t & 7) * 8;    // 0..56
  f32x4 acc[FM][FN] = {};
  for (int k0 = 0; k0 < Kk; k0 += 64) {
    #pragma unroll
    for (int p = 0; p < BM/32; ++p) {
      int r = p*32 + srow;
      int gr = m0 + r;
      bf16x8 av = {};
      if (gr < Mm) av = *(const bf16x8*)(A + (size_t)gr*lda + k0 + skseg);
      *(bf16x8*)(&As[r][skseg]) = av;
    }
    #pragma unroll
    for (int p = 0; p < BN/32; ++p) {
      int r = p*32 + srow;
      bf16x8 bv = *(const bf16x8*)(Bb + (size_t)(n0 + r)*ldb + k0 + skseg);
      *(bf16x8*)(&Bs[r][skseg]) = bv;
    }
    __syncthreads();
    #pragma unroll
    for (int kk = 0; kk < 64; kk += 32) {
      bf16x8 af[FM], bf[FN];
      #pragma unroll
      for (int i = 0; i < FM; ++i)
        af[i] = *(const bf16x8*)(&As[wm*(FM*16) + i*16 + lr][kk + lk]);
      #pragma unroll
      for (int i = 0; i < FN; ++i)
        bf[i] = *(const bf16x8*)(&Bs[wn*(FN*16) + i*16 + lr][kk + lk]);
      #pragma unroll
      for (int i = 0; i < FM; ++i)
        #pragma unroll
        for (int j = 0; j < FN; ++j)
          acc[i][j] = __builtin_amdgcn_mfma_f32_16x16x32_bf16(af[i], bf[j], acc[i][j], 0, 0, 0);
    }
    __syncthreads();
  }

  if constexpr (EPI == 4) {
    // fused max-pool over the wave's 32-row group (FM==2, Mm%64==0)
    #pragma unroll
    for (int ni = 0; ni < FN; ++ni) {
      int cc = n0 + wn*(FN*16) + ni*16 + lr;
      float mx = -3.0e38f;
      #pragma unroll
      for (int mi = 0; mi < FM; ++mi)
        #pragma unroll
        for (int j = 0; j < 4; ++j)
          mx = fmaxf(mx, acc[mi][ni][j]);
      mx = fmaxf(mx, __shfl_xor(mx, 16));
      mx = fmaxf(mx, __shfl_xor(mx, 32));
      if ((lane >> 4) == 0) {
        int ggl = poolG0 + (m0 >> 5) + wm;
        int b = ggl >> 7, g = ggl & 127;
        poolOut[((size_t)b*kNT + 1 + g)*kC + cc] = mx + bias[cc];
      }
    }
    return;
  }

  #pragma unroll
  for (int mi = 0; mi < FM; ++mi) {
    #pragma unroll
    for (int j = 0; j < 4; ++j) {
      int r = m0 + wm*(FM*16) + mi*16 + (lane >> 4)*4 + j;
      if (r < Mm) {
        #pragma unroll
        for (int ni = 0; ni < FN; ++ni) {
          int cc = n0 + wn*(FN*16) + ni*16 + lr;
          float v = acc[mi][ni][j];
          size_t o = (size_t)r*Nn + cc;
          if constexpr (EPI == 0) {
            ((unsigned short*)Cv)[o] = f2bf(v);
          } else if constexpr (EPI == 1) {
            ((unsigned short*)Cv)[o] = f2bf(v + bias[cc]);
          } else if constexpr (EPI == 2) {
            ((float*)Cv)[o] = v + bias[cc];
          } else if constexpr (EPI == 3) {
            float u = (v + aux[(size_t)(r >> 5)*Nn + cc])*gsc[cc] + bsc[cc];
            ((unsigned short*)Cv)[o] = f2bf(fmaxf(u, 0.0f));
          } else if constexpr (EPI == 5) {
            ((float*)Cv)[o] = aux[o] + v + bias[cc];
          } else {
            float u = v + bias[cc];
            ((unsigned short*)Cv)[o] = f2bf(0.5f*u*(1.0f + erff(u*0.70710678118654752440f)));
          }
        }
      }
    }
  }
}

// ----------------------------------------------------------- CLS token init
__global__ void cls_kernel(const float* __restrict__ ct, const float* __restrict__ cp,
                           float* __restrict__ x)
{
  int idx = blockIdx.x*256 + threadIdx.x;
  if (idx >= kB*kC) return;
  int b = idx / kC, c = idx % kC;
  x[(size_t)b*kNT*kC + c] = ct[c] + cp[c];
}

// ------------------------------------------------------------- LayerNorm
template <int OUTBF>
__global__ __launch_bounds__(256) void ln_kernel(
    const float* __restrict__ in, void* __restrict__ outv,
    const float* __restrict__ g, const float* __restrict__ bb)
{
  const int t = threadIdx.x;
  const int lane = t & 63;
  const int row = blockIdx.x*4 + (t >> 6);
  const float* p = in + (size_t)row*kC;
  float v[6];
  #pragma unroll
  for (int k = 0; k < 6; ++k) v[k] = p[k*64 + lane];
  float s = 0.f;
  #pragma unroll
  for (int k = 0; k < 6; ++k) s += v[k];
  #pragma unroll
  for (int off = 1; off < 64; off <<= 1) s += __shfl_xor(s, off);
  float mean = s / 384.0f;
  float vs = 0.f;
  #pragma unroll
  for (int k = 0; k < 6; ++k) { float d = v[k]-mean; vs += d*d; }
  #pragma unroll
  for (int off = 1; off < 64; off <<= 1) vs += __shfl_xor(vs, off);
  float r = rsqrtf(vs / 384.0f + 1e-5f);
  #pragma unroll
  for (int k = 0; k < 6; ++k) {
    int c = k*64 + lane;
    float o = (v[k]-mean)*r*g[c] + bb[c];
    if constexpr (OUTBF) ((unsigned short*)outv)[(size_t)row*kC + c] = f2bf(o);
    else                 ((float*)outv)[(size_t)row*kC + c] = o;
  }
}

// ------------------------------------------------------------- attention
__global__ __launch_bounds__(512) void attn_kernel(
    const unsigned short* __restrict__ qkv, const float* __restrict__ pcs,
    const float* __restrict__ psn, const float* __restrict__ gth,
    unsigned short* __restrict__ o)
{
  __shared__ float qs[kNT][kHD];
  __shared__ float ks[kNT][kHD];
  __shared__ float vls[kNT][kHD];
  __shared__ float gcs[24], gss[24];
  __shared__ float ps[8][132];
  const int t = threadIdx.x;
  const int bh = blockIdx.x;
  const int b = bh >> 3, hh = bh & 7;
  if (t < 24) { float th = gth[hh*24 + t]; gcs[t] = cosf(th); gss[t] = sinf(th); }
  __syncthreads();
  for (int idx = t; idx < kNT*24; idx += 512) {
    int n = idx / 24, p = idx % 24;
    const unsigned short* base = qkv + ((size_t)(b*kNT + n))*1152 + hh*kHD + 2*p;
    float q0 = bf2f(base[0]),   q1 = bf2f(base[1]);
    float k0 = bf2f(base[384]), k1 = bf2f(base[385]);
    float v0 = bf2f(base[768]), v1 = bf2f(base[769]);
    float cg = gcs[p], sg = gss[p];
    float qr = q0*cg - q1*sg, qi = q0*sg + q1*cg;
    float kr = k0*cg - k1*sg, ki = k0*sg + k1*cg;
    if (n > 0) {
      size_t pi = ((size_t)b*kG + (n-1))*24 + p;
      float pc = pcs[pi], pv = psn[pi];
      float tq = qr*pc - qi*pv; qi = qr*pv + qi*pc; qr = tq;
      float tk = kr*pc - ki*pv; ki = kr*pv + ki*pc; kr = tk;
    }
    qs[n][2*p] = qr; qs[n][2*p+1] = qi;
    ks[n][2*p] = kr; ks[n][2*p+1] = ki;
    vls[n][2*p] = v0; vls[n][2*p+1] = v1;
  }
  __syncthreads();
  const int lane = t & 63, w = t >> 6;
  for (int r = w; r < kNT; r += 8) {
    float4 q[12];
    #pragma unroll
    for (int d = 0; d < 12; ++d) q[d] = *(const float4*)(&qs[r][d*4]);
    float sv[3];
    float mx = -3.0e38f;
    #pragma unroll
    for (int ji = 0; ji < 3; ++ji) {
      int j = ji*64 + lane;
      float s = -3.0e38f;
      if (j < kNT) {
        float a0 = 0.f, a1 = 0.f;
        #pragma unroll
        for (int d = 0; d < 12; d += 2) {
          float4 k0v = *(const float4*)(&ks[j][d*4]);
          float4 k1v = *(const float4*)(&ks[j][d*4+4]);
          a0 += q[d].x*k0v.x + q[d].y*k0v.y + q[d].z*k0v.z + q[d].w*k0v.w;
          a1 += q[d+1].x*k1v.x + q[d+1].y*k1v.y + q[d+1].z*k1v.z + q[d+1].w*k1v.w;
        }
        s = (a0 + a1) * 0.14433756729740643f;
      }
      sv[ji] = s;
      mx = fmaxf(mx, s);
    }
    #pragma unroll
    for (int off = 1; off < 64; off <<= 1) mx = fmaxf(mx, __shfl_xor(mx, off));
    float sum = 0.f;
    #pragma unroll
    for (int ji = 0; ji < 3; ++ji) {
      int j = ji*64 + lane;
      if (j < kNT) { float e = expf(sv[ji] - mx); ps[w][j] = e; sum += e; }
    }
    #pragma unroll
    for (int off = 1; off < 64; off <<= 1) sum += __shfl_xor(sum, off);
    if (lane < kHD) {
      float ac0 = 0.f, ac1 = 0.f, ac2 = 0.f, ac3 = 0.f;
      for (int j4 = 0; j4 < 128; j4 += 16) {
        float4 p0 = *(const float4*)(&ps[w][j4]);
        float4 p1 = *(const float4*)(&ps[w][j4+4]);
        float4 p2 = *(const float4*)(&ps[w][j4+8]);
        float4 p3 = *(const float4*)(&ps[w][j4+12]);
        ac0 += p0.x*vls[j4+0][lane] + p0.y*vls[j4+1][lane]
             + p0.z*vls[j4+2][lane] + p0.w*vls[j4+3][lane];
        ac1 += p1.x*vls[j4+4][lane] + p1.y*vls[j4+5][lane]
             + p1.z*vls[j4+6][lane] + p1.w*vls[j4+7][lane];
        ac2 += p2.x*vls[j4+8][lane] + p2.y*vls[j4+9][lane]
             + p2.z*vls[j4+10][lane] + p2.w*vls[j4+11][lane];
        ac3 += p3.x*vls[j4+12][lane] + p3.y*vls[j4+13][lane]
             + p3.z*vls[j4+14][lane] + p3.w*vls[j4+15][lane];
      }
      float accv = ((ac0 + ac1) + (ac2 + ac3)) + ps[w][128]*vls[128][lane];
      o[((size_t)(b*kNT + r))*kC + hh*kHD + lane] = f2bf(accv / sum);
    }
  }
}

// ------------------------------------------------------------- head
__global__ __launch_bounds__(256) void head_kernel(
    const float* __restrict__ xf,
    const float* __restrict__ hw1, const float* __restrict__ hb1,
    const float* __restrict__ hg1, const float* __restrict__ hbe1,
    const float* __restrict__ hw2, const float* __restrict__ hb2,
    const float* __restrict__ hg2, const float* __restrict__ hbe2,
    const float* __restrict__ hw3, const float* __restrict__ hb3,
    float* __restrict__ out)
{
  __shared__ float f[768];
  __shared__ float h1[256], h2[256];
  const int t = threadIdx.x;
  const int b = blockIdx.x;
  const float* xb = xf + (size_t)b*kNT*kC;
  for (int c = t; c < kC; c += 256) {
    f[c] = xb[c];
    float mx = -3.0e38f;
    for (int n = 1; n < kNT; ++n) mx = fmaxf(mx, xb[(size_t)n*kC + c]);
    f[kC + c] = mx;
  }
  __syncthreads();
  {
    float acc = hb1[t];
    for (int k = 0; k < 768; k += 4) {
      float4 wv = *(const float4*)(hw1 + (size_t)t*768 + k);
      float4 fv = *(const float4*)(&f[k]);
      acc += fv.x*wv.x + fv.y*wv.y + fv.z*wv.z + fv.w*wv.w;
    }
    h1[t] = fmaxf(acc*hg1[t] + hbe1[t], 0.0f);
  }
  __syncthreads();
  {
    float acc = hb2[t];
    for (int k = 0; k < 256; k += 4) {
      float4 wv = *(const float4*)(hw2 + (size_t)t*256 + k);
      float4 fv = *(const float4*)(&h1[k]);
      acc += fv.x*wv.x + fv.y*wv.y + fv.z*wv.z + fv.w*wv.w;
    }
    h2[t] = fmaxf(acc*hg2[t] + hbe2[t], 0.0f);
  }
  __syncthreads();
  if (t < 40) {
    float acc = hb3[t];
    for (int k = 0; k < 256; k += 4) {
      float4 wv = *(const float4*)(hw3 + (size_t)t*256 + k);
      float4 fv = *(const float4*)(&h2[k]);
      acc += fv.x*wv.x + fv.y*wv.y + fv.z*wv.z + fv.w*wv.w;
    }
    out[(size_t)b*40 + t] = acc;
  }
}

// ------------------------------------------------------------- launch
extern "C" void kernel_launch(void* const* d_in, const int* in_sizes, int n_in,
                              void* d_out, int out_size, void* d_ws, size_t ws_size,
                              hipStream_t stream) {
  const float* pts     = (const float*)d_in[0];
  const float* enc_w1  = (const float*)d_in[1];
  const float* enc_b1  = (const float*)d_in[2];
  const float* enc_g1  = (const float*)d_in[3];
  const float* enc_be1 = (const float*)d_in[4];
  const float* enc_w2  = (const float*)d_in[5];
  const float* enc_b2  = (const float*)d_in[6];
  const float* enc_w3  = (const float*)d_in[7];
  const float* enc_b3  = (const float*)d_in[8];
  const float* enc_g2  = (const float*)d_in[9];
  const float* enc_be2 = (const float*)d_in[10];
  const float* enc_w4  = (const float*)d_in[11];
  const float* enc_b4  = (const float*)d_in[12];
  const float* cls_tok = (const float*)d_in[13];
  const float* cls_pos = (const float*)d_in[14];
  const float* ln1_g   = (const float*)d_in[15];
  const float* ln1_b   = (const float*)d_in[16];
  const float* qkv_w   = (const float*)d_in[17];
  const float* givens  = (const float*)d_in[18];
  const float* proj_w  = (const float*)d_in[19];
  const float* proj_b  = (const float*)d_in[20];
  const float* ln2_g   = (const float*)d_in[21];
  const float* ln2_b   = (const float*)d_in[22];
  const float* fc1_w   = (const float*)d_in[23];
  const float* fc1_b   = (const float*)d_in[24];
  const float* fc2_w   = (const float*)d_in[25];
  const float* fc2_b   = (const float*)d_in[26];
  const float* norm_g  = (const float*)d_in[27];
  const float* norm_b  = (const float*)d_in[28];
  const float* hw1     = (const float*)d_in[29];
  const float* hb1     = (const float*)d_in[30];
  const float* hg1     = (const float*)d_in[31];
  const float* hbe1    = (const float*)d_in[32];
  const float* hw2     = (const float*)d_in[33];
  const float* hb2     = (const float*)d_in[34];
  const float* hg2     = (const float*)d_in[35];
  const float* hbe2    = (const float*)d_in[36];
  const float* hw3     = (const float*)d_in[37];
  const float* hb3     = (const float*)d_in[38];

  char* wsb = (char*)d_ws;
  size_t off = 0;
  float* center = (float*)(wsb + off); off += (size_t)kB*kG*3*4;        // 48K
  float* pcs    = (float*)(wsb + off); off += (size_t)kB*kG*24*4;       // 384K
  float* psn    = (float*)(wsb + off); off += (size_t)kB*kG*24*4;       // 384K
  float* neigh  = (float*)(wsb + off); off += (size_t)kB*kG*kM*3*4;     // 1.5M
  float* xbuf   = (float*)(wsb + off); off += (size_t)kRows*kC*4;       // 6.34M
  // bf16 weight caches
  unsigned short* encwb = (unsigned short*)(wsb + off); off += 491520ull*2;   // w2|w3|w4
  unsigned short* wlbf  = (unsigned short*)(wsb + off); off += 1769472ull*2;  // per-layer qkv|proj|fc1|fc2
  char* scratch = wsb + off;
  // encoder view of scratch (f3c aliases f1c region: disjoint lifetimes)
  unsigned short* f3c   = (unsigned short*)(scratch);                    // 16.78M
  unsigned short* f1c   = (unsigned short*)(scratch);                    // 4.19M (dead before f3c written)
  unsigned short* f2c   = (unsigned short*)(scratch + 16777216);         // 8.39M
  unsigned short* fgc   = (unsigned short*)(scratch + 16777216 + 8388608);         // 0.26M
  float*          basec = (float*)(scratch + 16777216 + 8388608 + 262144);         // 1.05M
  // transformer view of scratch (mlpb aliases qkvb+attnob; flnb aliases qkvb)
  unsigned short* hbuf   = (unsigned short*)(scratch);                   // 3.17M
  unsigned short* qkvb   = (unsigned short*)(scratch + 3170304);         // 9.51M
  unsigned short* attnob = (unsigned short*)(scratch + 3170304 + 9510912); // 3.17M
  unsigned short* mlpb   = (unsigned short*)(scratch + 3170304);         // 12.68M (qkv+attn dead)
  float*          flnb   = (float*)(scratch + 3170304);                  // post-loop

  const unsigned short* encw2 = encwb;
  const unsigned short* encw3 = encwb + 32768;
  const unsigned short* encw4 = encwb + 32768 + 262144;

  fps_kernel<<<kB, 64, 0, stream>>>(pts, center);
  rope_kernel<<<(kB*kG*24 + 255)/256, 256, 0, stream>>>(center, pcs, psn);
  knn_kernel<<<kB*kG/4, 256, 0, stream>>>(pts, center, neigh);

  // encoder weight cache (once)
  wcvt_kernel<<<32768/8/256, 256, 0, stream>>>(enc_w2, (unsigned short*)encw2, 32768);
  wcvt_kernel<<<262144/8/256, 256, 0, stream>>>(enc_w3, (unsigned short*)encw3, 262144);
  wcvt_kernel<<<196608/8/256, 256, 0, stream>>>(enc_w4, (unsigned short*)encw4, 196608);

  // ---- encoder: 8 chunks of 512 groups (16384 rows) ----
  for (int c = 0; c < 8; ++c) {
    const float* nc = neigh + (size_t)c*kRC*3;
    enc1_kernel<<<kRC/2, 256, 0, stream>>>(nc, enc_w1, enc_b1, enc_g1, enc_be1, f1c);
    mgemm_kernel<1,2,2><<<dim3(kRC/64, 4), 256, 0, stream>>>(
        f1c, 128, encw2, 128, f2c, enc_b2, nullptr, nullptr, nullptr,
        kRC, 256, 128, nullptr, 0);
    pool2_kernel<<<kGC, 256, 0, stream>>>(f2c, fgc);
    mgemm_kernel<2,2,2><<<dim3(kGC/64, 8), 256, 0, stream>>>(
        fgc, 256, encw3, 512, basec, enc_b3, nullptr, nullptr, nullptr,
        kGC, 512, 256, nullptr, 0);
    mgemm_kernel<3,2,2><<<dim3(kRC/64, 8), 256, 0, stream>>>(
        f2c, 256, encw3 + 256, 512, f3c, nullptr, basec, enc_g2, enc_be2,
        kRC, 512, 256, nullptr, 0);
    mgemm_kernel<4,2,2><<<dim3(kRC/64, 6), 256, 0, stream>>>(
        f3c, 512, encw4, 512, nullptr, enc_b4, nullptr, nullptr, nullptr,
        kRC, 384, 512, xbuf, c*kGC);
  }
  cls_kernel<<<(kB*kC + 255)/256, 256, 0, stream>>>(cls_tok, cls_pos, xbuf);

  const unsigned short* wq = wlbf;
  const unsigned short* wp = wlbf + 442368;
  const unsigned short* w1f = wlbf + 589824;
  const unsigned short* w2f = wlbf + 1179648;
  const int lnGrid = kRows/4;
  for (int l = 0; l < 12; ++l) {
    wcvt4_kernel<<<864, 256, 0, stream>>>(
        qkv_w + (size_t)l*442368, proj_w + (size_t)l*147456,
        fc1_w + (size_t)l*589824, fc2_w + (size_t)l*589824, wlbf);
    ln_kernel<1><<<lnGrid, 256, 0, stream>>>(xbuf, hbuf, ln1_g + l*kC, ln1_b + l*kC);
    mgemm_kernel<0,2,2><<<dim3(65, 18), 256, 0, stream>>>(
        hbuf, kC, wq, kC, qkvb, nullptr, nullptr, nullptr, nullptr,
        kRows, 1152, kC, nullptr, 0);
    attn_kernel<<<kB*kH, 512, 0, stream>>>(qkvb, pcs, psn, givens + (size_t)l*kH*24, attnob);
    mgemm_kernel<5,2,2><<<dim3(65, 6), 256, 0, stream>>>(
        attnob, kC, wp, kC, xbuf, proj_b + l*kC, xbuf, nullptr, nullptr,
        kRows, kC, kC, nullptr, 0);
    ln_kernel<1><<<lnGrid, 256, 0, stream>>>(xbuf, hbuf, ln2_g + l*kC, ln2_b + l*kC);
    mgemm_kernel<6,2,2><<<dim3(65, 24), 256, 0, stream>>>(
        hbuf, kC, w1f, kC, mlpb, fc1_b + l*kMLP, nullptr, nullptr, nullptr,
        kRows, kMLP, kC, nullptr, 0);
    mgemm_kernel<5,2,2><<<dim3(65, 6), 256, 0, stream>>>(
        mlpb, kMLP, w2f, kMLP, xbuf, fc2_b + l*kC, xbuf, nullptr, nullptr,
        kRows, kC, kMLP, nullptr, 0);
  }
  ln_kernel<0><<<lnGrid, 256, 0, stream>>>(xbuf, flnb, norm_g, norm_b);
  head_kernel<<<kB, 256, 0, stream>>>(flnb,
      hw1, hb1, hg1, hbe1, hw2, hb2, hg2, hbe2, hw3, hb3, (float*)d_out);
}

// Round 7
// 2411.381 us; speedup vs baseline: 4.1672x; 1.0013x over previous
//
#include <hip/hip_runtime.h>
#include <math.h>

// Problem constants
constexpr int kB   = 32;     // batch
constexpr int kN   = 2048;   // raw points
constexpr int kG   = 128;    // groups (FPS centers)
constexpr int kM   = 32;     // group size (KNN)
constexpr int kC   = 384;    // trans dim
constexpr int kH   = 8;      // heads
constexpr int kHD  = 48;     // head dim
constexpr int kNT  = 129;    // tokens (CLS + groups)
constexpr int kMLP = 1536;
constexpr int kRows = kB * kNT; // 4128
constexpr int kGC  = 512;       // encoder groups per chunk
constexpr int kRC  = kGC * kM;  // encoder rows per chunk = 16384

typedef __attribute__((ext_vector_type(8))) short bf16x8;
typedef __attribute__((ext_vector_type(4))) float f32x4;

__device__ __forceinline__ unsigned short f2bf(float x) {
  unsigned u = __float_as_uint(x);
  unsigned r = (u + 0x7fffu + ((u >> 16) & 1u)) >> 16;
  return (unsigned short)r;
}
__device__ __forceinline__ float bf2f(unsigned short u) {
  return __uint_as_float(((unsigned)u) << 16);
}

// ---------------------------------------------------------------- FPS
// Single wave per batch; 32 points/lane in registers. SCALAR arithmetic,
// contract off, (dx2+dy2)+dz2 order — bit-exact vs the JAX reference scan
// (selection-identical to the round-4 pass; only LDS layout + VGPR budget
// changed, both value-neutral). launch_bounds(64,1) keeps rx/ry/rz/rd
// (128 floats) in registers; stride-33 LDS staging is conflict-free.
__global__ __launch_bounds__(64, 1) void fps_kernel(
    const float* __restrict__ pts, float* __restrict__ center)
{
  #pragma clang fp contract(off)
  __shared__ float sx[kN + 64], sy[kN + 64], sz[kN + 64];
  const int b = blockIdx.x, lane = threadIdx.x;
  const float* P = pts + (size_t)b * kN * 3;
  float rx[32], ry[32], rz[32], rd[32];
  const int base = lane * 32;
  #pragma unroll
  for (int j = 0; j < 32; ++j) {
    int i = base + j;
    float x = P[3*i], y = P[3*i+1], z = P[3*i+2];
    rx[j] = x; ry[j] = y; rz[j] = z; rd[j] = 1e10f;
    int ii = lane*33 + j;            // i + (i>>5) swizzle: conflict-free
    sx[ii] = x; sy[ii] = y; sz[ii] = z;
  }
  __syncthreads();
  int last = 0;
  float* cb = center + (size_t)b * kG * 3;
  for (int it = 0; it < kG; ++it) {
    int ls = last + (last >> 5);
    float lx = sx[ls], ly = sy[ls], lz = sz[ls];   // uniform broadcast
    if (lane == 0) { cb[3*it] = lx; cb[3*it+1] = ly; cb[3*it+2] = lz; }
    float bestv = -1.0f; int besti = kN;
    #pragma unroll
    for (int j = 0; j < 32; ++j) {
      float dx = rx[j]-lx, dy = ry[j]-ly, dz = rz[j]-lz;
      float d = (dx*dx + dy*dy) + dz*dz;
      float nd = fminf(rd[j], d);
      rd[j] = nd;
      if (nd > bestv) { bestv = nd; besti = base + j; }
    }
    #pragma unroll
    for (int off = 1; off < 64; off <<= 1) {
      float vv = __shfl_xor(bestv, off);
      int   ii = __shfl_xor(besti, off);
      if (vv > bestv || (vv == bestv && ii < besti)) { bestv = vv; besti = ii; }
    }
    last = besti;
  }
}

// ------------------------------------------------------- RoPE cos/sin table
__global__ void rope_kernel(const float* __restrict__ center,
                            float* __restrict__ pcs, float* __restrict__ psn)
{
  int idx = blockIdx.x*256 + threadIdx.x;
  if (idx >= kB*kG*24) return;
  int p  = idx % 24;
  int bg = idx / 24;
  int axis = p >> 3, j = p & 7;
  float e  = (float)(2*j) / 16.0f;
  float fr = 1.0f / powf(100.0f, e);
  float ang = center[(size_t)bg*3 + axis] * fr;
  pcs[idx] = cosf(ang);
  psn[idx] = sinf(ang);
}

// ---------------------------------------------------------------- KNN
__global__ __launch_bounds__(256) void knn_kernel(
    const float* __restrict__ pts, const float* __restrict__ center,
    float* __restrict__ neigh)
{
  #pragma clang fp contract(off)
  __shared__ float sx[kN + kN/32], sy[kN + kN/32], sz[kN + kN/32];
  const int t = threadIdx.x;
  const int lane = t & 63, w = t >> 6;
  const int blk = blockIdx.x;          // 1024 blocks; 32 per batch, 4 groups each
  const int b = blk >> 5;
  const float* P = pts + (size_t)b * kN * 3;
  for (int i = t; i < kN; i += 256) {
    int ii = i + (i >> 5);
    sx[ii] = P[3*i]; sy[ii] = P[3*i+1]; sz[ii] = P[3*i+2];
  }
  __syncthreads();
  const int bg = b*kG + (blk & 31)*4 + w;
  const float cx = center[(size_t)bg*3+0];
  const float cy = center[(size_t)bg*3+1];
  const float cz = center[(size_t)bg*3+2];
  float rd[32];
  const int base = lane * 32;
  #pragma unroll
  for (int j = 0; j < 32; ++j) {
    int is = lane*33 + j;
    float dx = cx - sx[is], dy = cy - sy[is], dz = cz - sz[is];
    rd[j] = (dx*dx + dy*dy) + dz*dz;
  }
  float* ob = neigh + (size_t)bg * kM * 3;
  int lastWin = -1;
  for (int m = 0; m < kM; ++m) {
    float bestv = 3.0e38f; int besti = kN;
    #pragma unroll
    for (int j = 0; j < 32; ++j) {
      float v = rd[j];
      if (base + j == lastWin) v = 3.0e38f;
      rd[j] = v;
      if (v < bestv) { bestv = v; besti = base + j; }
    }
    #pragma unroll
    for (int off = 1; off < 64; off <<= 1) {
      float vv = __shfl_xor(bestv, off);
      int   i2 = __shfl_xor(besti, off);
      if (vv < bestv || (vv == bestv && i2 < besti)) { bestv = vv; besti = i2; }
    }
    lastWin = besti;
    if (lane == 0) {
      int is = besti + (besti >> 5);
      ob[3*m+0] = sx[is] - cx; ob[3*m+1] = sy[is] - cy; ob[3*m+2] = sz[is] - cz;
    }
  }
}

// ------------------------------------------------- weight cvt fp32 -> bf16
__global__ void wcvt_kernel(const float* __restrict__ s,
                            unsigned short* __restrict__ d, int n)
{
  int i = (blockIdx.x*256 + threadIdx.x)*8;
  if (i >= n) return;
  float4 a = *(const float4*)(s + i), b = *(const float4*)(s + i + 4);
  bf16x8 v;
  v[0]=(short)f2bf(a.x); v[1]=(short)f2bf(a.y); v[2]=(short)f2bf(a.z); v[3]=(short)f2bf(a.w);
  v[4]=(short)f2bf(b.x); v[5]=(short)f2bf(b.y); v[6]=(short)f2bf(b.z); v[7]=(short)f2bf(b.w);
  *(bf16x8*)(d + i) = v;
}

// per-layer fused conversion of qkv|proj|fc1|fc2 (1769472 elements total)
__global__ void wcvt4_kernel(const float* __restrict__ q, const float* __restrict__ p,
                             const float* __restrict__ f1, const float* __restrict__ f2,
                             unsigned short* __restrict__ d)
{
  int i = (blockIdx.x*256 + threadIdx.x)*8;   // grid sized exactly
  const float* s; int lo;
  if (i < 442368)       { s = q;  lo = i; }
  else if (i < 589824)  { s = p;  lo = i - 442368; }
  else if (i < 1179648) { s = f1; lo = i - 589824; }
  else                  { s = f2; lo = i - 1179648; }
  float4 a = *(const float4*)(s + lo), b = *(const float4*)(s + lo + 4);
  bf16x8 v;
  v[0]=(short)f2bf(a.x); v[1]=(short)f2bf(a.y); v[2]=(short)f2bf(a.z); v[3]=(short)f2bf(a.w);
  v[4]=(short)f2bf(b.x); v[5]=(short)f2bf(b.y); v[6]=(short)f2bf(b.z); v[7]=(short)f2bf(b.w);
  *(bf16x8*)(d + i) = v;
}

// ------------------------------------------------- encoder layer1 (3->128)
__global__ __launch_bounds__(256) void enc1_kernel(
    const float* __restrict__ neighC,
    const float* __restrict__ w1, const float* __restrict__ b1,
    const float* __restrict__ g1, const float* __restrict__ be1,
    unsigned short* __restrict__ f1c)
{
  const int t = threadIdx.x;
  const int r = blockIdx.x*2 + (t >> 7);
  const int c = t & 127;
  const float* nr = neighC + (size_t)r*3;
  float x0 = nr[0], x1 = nr[1], x2 = nr[2];
  float s = x0*w1[3*c] + x1*w1[3*c+1] + x2*w1[3*c+2] + b1[c];
  float v = fmaxf(s*g1[c] + be1[c], 0.0f);
  f1c[(size_t)r*128 + c] = f2bf(v);
}

// ------------------------------------------------- encoder fg pool (layer2 max)
__global__ __launch_bounds__(256) void pool2_kernel(
    const unsigned short* __restrict__ f2c, unsigned short* __restrict__ fgc)
{
  const int g = blockIdx.x, c = threadIdx.x;
  float mx = -3.0e38f;
  #pragma unroll 8
  for (int m = 0; m < kM; ++m)
    mx = fmaxf(mx, bf2f(f2c[((size_t)g*kM + m)*256 + c]));
  fgc[(size_t)g*256 + c] = f2bf(mx);
}

// ------------------------------------------------------------- MFMA GEMM
// Out[M,N] (+epilogue) = A[M,K](bf16,lda) @ B[N,K](bf16,ldb)^T
// Block tile BMxBN (BM=FM*32, BN=FN*32); BK=64; 256 thr = 4 waves (2x2).
// EPI: 0 bf16 plain | 1 bf16 +bias | 2 f32 +bias | 3 bf16 relu((v+base[r>>5])*g+be)
//      4 fused 32-row max-pool (+bias) -> tokens (FM==2) | 5 f32 res+v+bias | 6 bf16 gelu(v+bias)
template <int EPI, int FM, int FN>
__global__ __launch_bounds__(256) void mgemm_kernel(
    const unsigned short* __restrict__ A, int lda,
    const unsigned short* __restrict__ Bb, int ldb,
    void* __restrict__ Cv,
    const float* __restrict__ bias,
    const float* __restrict__ aux,       // res (EPI5) or base (EPI3)
    const float* __restrict__ gsc, const float* __restrict__ bsc,  // EPI3
    int Mm, int Nn, int Kk,
    float* __restrict__ poolOut, int poolG0)
{
  constexpr int BM = FM*32, BN = FN*32;
  __shared__ unsigned short As[BM][72];
  __shared__ unsigned short Bs[BN][72];
  const int t = threadIdx.x;
  const int m0 = blockIdx.x * BM;
  const int n0 = blockIdx.y * BN;
  const int w = t >> 6, lane = t & 63;
  const int wm = w >> 1, wn = w & 1;
  const int lr = lane & 15;
  const int lk = (lane >> 4) * 8;
  const int srow = t >> 3;          // 0..31
  const int skseg = (t & 7) * 8;    // 0..56
  f32x4 acc[FM][FN] = {};
  for (int k0 = 0; k0 < Kk; k0 += 64) {
    #pragma unroll
    for (int p = 0; p < BM/32; ++p) {
      int r = p*32 + srow;
      int gr = m0 + r;
      bf16x8 av = {};
      if (gr < Mm) av = *(const bf16x8*)(A + (size_t)gr*lda + k0 + skseg);
      *(bf16x8*)(&As[r][skseg]) = av;
    }
    #pragma unroll
    for (int p = 0; p < BN/32; ++p) {
      int r = p*32 + srow;
      bf16x8 bv = *(const bf16x8*)(Bb + (size_t)(n0 + r)*ldb + k0 + skseg);
      *(bf16x8*)(&Bs[r][skseg]) = bv;
    }
    __syncthreads();
    #pragma unroll
    for (int kk = 0; kk < 64; kk += 32) {
      bf16x8 af[FM], bf[FN];
      #pragma unroll
      for (int i = 0; i < FM; ++i)
        af[i] = *(const bf16x8*)(&As[wm*(FM*16) + i*16 + lr][kk + lk]);
      #pragma unroll
      for (int i = 0; i < FN; ++i)
        bf[i] = *(const bf16x8*)(&Bs[wn*(FN*16) + i*16 + lr][kk + lk]);
      #pragma unroll
      for (int i = 0; i < FM; ++i)
        #pragma unroll
        for (int j = 0; j < FN; ++j)
          acc[i][j] = __builtin_amdgcn_mfma_f32_16x16x32_bf16(af[i], bf[j], acc[i][j], 0, 0, 0);
    }
    __syncthreads();
  }

  if constexpr (EPI == 4) {
    // fused max-pool over the wave's 32-row group (FM==2, Mm%64==0)
    #pragma unroll
    for (int ni = 0; ni < FN; ++ni) {
      int cc = n0 + wn*(FN*16) + ni*16 + lr;
      float mx = -3.0e38f;
      #pragma unroll
      for (int mi = 0; mi < FM; ++mi)
        #pragma unroll
        for (int j = 0; j < 4; ++j)
          mx = fmaxf(mx, acc[mi][ni][j]);
      mx = fmaxf(mx, __shfl_xor(mx, 16));
      mx = fmaxf(mx, __shfl_xor(mx, 32));
      if ((lane >> 4) == 0) {
        int ggl = poolG0 + (m0 >> 5) + wm;
        int b = ggl >> 7, g = ggl & 127;
        poolOut[((size_t)b*kNT + 1 + g)*kC + cc] = mx + bias[cc];
      }
    }
    return;
  }

  #pragma unroll
  for (int mi = 0; mi < FM; ++mi) {
    #pragma unroll
    for (int j = 0; j < 4; ++j) {
      int r = m0 + wm*(FM*16) + mi*16 + (lane >> 4)*4 + j;
      if (r < Mm) {
        #pragma unroll
        for (int ni = 0; ni < FN; ++ni) {
          int cc = n0 + wn*(FN*16) + ni*16 + lr;
          float v = acc[mi][ni][j];
          size_t o = (size_t)r*Nn + cc;
          if constexpr (EPI == 0) {
            ((unsigned short*)Cv)[o] = f2bf(v);
          } else if constexpr (EPI == 1) {
            ((unsigned short*)Cv)[o] = f2bf(v + bias[cc]);
          } else if constexpr (EPI == 2) {
            ((float*)Cv)[o] = v + bias[cc];
          } else if constexpr (EPI == 3) {
            float u = (v + aux[(size_t)(r >> 5)*Nn + cc])*gsc[cc] + bsc[cc];
            ((unsigned short*)Cv)[o] = f2bf(fmaxf(u, 0.0f));
          } else if constexpr (EPI == 5) {
            ((float*)Cv)[o] = aux[o] + v + bias[cc];
          } else {
            float u = v + bias[cc];
            ((unsigned short*)Cv)[o] = f2bf(0.5f*u*(1.0f + erff(u*0.70710678118654752440f)));
          }
        }
      }
    }
  }
}

// ----------------------------------------------------------- CLS token init
__global__ void cls_kernel(const float* __restrict__ ct, const float* __restrict__ cp,
                           float* __restrict__ x)
{
  int idx = blockIdx.x*256 + threadIdx.x;
  if (idx >= kB*kC) return;
  int b = idx / kC, c = idx % kC;
  x[(size_t)b*kNT*kC + c] = ct[c] + cp[c];
}

// ------------------------------------------------------------- LayerNorm
template <int OUTBF>
__global__ __launch_bounds__(256) void ln_kernel(
    const float* __restrict__ in, void* __restrict__ outv,
    const float* __restrict__ g, const float* __restrict__ bb)
{
  const int t = threadIdx.x;
  const int lane = t & 63;
  const int row = blockIdx.x*4 + (t >> 6);
  const float* p = in + (size_t)row*kC;
  float v[6];
  #pragma unroll
  for (int k = 0; k < 6; ++k) v[k] = p[k*64 + lane];
  float s = 0.f;
  #pragma unroll
  for (int k = 0; k < 6; ++k) s += v[k];
  #pragma unroll
  for (int off = 1; off < 64; off <<= 1) s += __shfl_xor(s, off);
  float mean = s / 384.0f;
  float vs = 0.f;
  #pragma unroll
  for (int k = 0; k < 6; ++k) { float d = v[k]-mean; vs += d*d; }
  #pragma unroll
  for (int off = 1; off < 64; off <<= 1) vs += __shfl_xor(vs, off);
  float r = rsqrtf(vs / 384.0f + 1e-5f);
  #pragma unroll
  for (int k = 0; k < 6; ++k) {
    int c = k*64 + lane;
    float o = (v[k]-mean)*r*g[c] + bb[c];
    if constexpr (OUTBF) ((unsigned short*)outv)[(size_t)row*kC + c] = f2bf(o);
    else                 ((float*)outv)[(size_t)row*kC + c] = o;
  }
}

// ------------------------------------------------------------- attention
__global__ __launch_bounds__(512) void attn_kernel(
    const unsigned short* __restrict__ qkv, const float* __restrict__ pcs,
    const float* __restrict__ psn, const float* __restrict__ gth,
    unsigned short* __restrict__ o)
{
  __shared__ float qs[kNT][kHD];
  __shared__ float ks[kNT][kHD];
  __shared__ float vls[kNT][kHD];
  __shared__ float gcs[24], gss[24];
  __shared__ float ps[8][132];
  const int t = threadIdx.x;
  const int bh = blockIdx.x;
  const int b = bh >> 3, hh = bh & 7;
  if (t < 24) { float th = gth[hh*24 + t]; gcs[t] = cosf(th); gss[t] = sinf(th); }
  __syncthreads();
  for (int idx = t; idx < kNT*24; idx += 512) {
    int n = idx / 24, p = idx % 24;
    const unsigned short* base = qkv + ((size_t)(b*kNT + n))*1152 + hh*kHD + 2*p;
    float q0 = bf2f(base[0]),   q1 = bf2f(base[1]);
    float k0 = bf2f(base[384]), k1 = bf2f(base[385]);
    float v0 = bf2f(base[768]), v1 = bf2f(base[769]);
    float cg = gcs[p], sg = gss[p];
    float qr = q0*cg - q1*sg, qi = q0*sg + q1*cg;
    float kr = k0*cg - k1*sg, ki = k0*sg + k1*cg;
    if (n > 0) {
      size_t pi = ((size_t)b*kG + (n-1))*24 + p;
      float pc = pcs[pi], pv = psn[pi];
      float tq = qr*pc - qi*pv; qi = qr*pv + qi*pc; qr = tq;
      float tk = kr*pc - ki*pv; ki = kr*pv + ki*pc; kr = tk;
    }
    qs[n][2*p] = qr; qs[n][2*p+1] = qi;
    ks[n][2*p] = kr; ks[n][2*p+1] = ki;
    vls[n][2*p] = v0; vls[n][2*p+1] = v1;
  }
  __syncthreads();
  const int lane = t & 63, w = t >> 6;
  for (int r = w; r < kNT; r += 8) {
    float4 q[12];
    #pragma unroll
    for (int d = 0; d < 12; ++d) q[d] = *(const float4*)(&qs[r][d*4]);
    float sv[3];
    float mx = -3.0e38f;
    #pragma unroll
    for (int ji = 0; ji < 3; ++ji) {
      int j = ji*64 + lane;
      float s = -3.0e38f;
      if (j < kNT) {
        float a0 = 0.f, a1 = 0.f;
        #pragma unroll
        for (int d = 0; d < 12; d += 2) {
          float4 k0v = *(const float4*)(&ks[j][d*4]);
          float4 k1v = *(const float4*)(&ks[j][d*4+4]);
          a0 += q[d].x*k0v.x + q[d].y*k0v.y + q[d].z*k0v.z + q[d].w*k0v.w;
          a1 += q[d+1].x*k1v.x + q[d+1].y*k1v.y + q[d+1].z*k1v.z + q[d+1].w*k1v.w;
        }
        s = (a0 + a1) * 0.14433756729740643f;
      }
      sv[ji] = s;
      mx = fmaxf(mx, s);
    }
    #pragma unroll
    for (int off = 1; off < 64; off <<= 1) mx = fmaxf(mx, __shfl_xor(mx, off));
    float sum = 0.f;
    #pragma unroll
    for (int ji = 0; ji < 3; ++ji) {
      int j = ji*64 + lane;
      if (j < kNT) { float e = expf(sv[ji] - mx); ps[w][j] = e; sum += e; }
    }
    #pragma unroll
    for (int off = 1; off < 64; off <<= 1) sum += __shfl_xor(sum, off);
    if (lane < kHD) {
      float ac0 = 0.f, ac1 = 0.f, ac2 = 0.f, ac3 = 0.f;
      for (int j4 = 0; j4 < 128; j4 += 16) {
        float4 p0 = *(const float4*)(&ps[w][j4]);
        float4 p1 = *(const float4*)(&ps[w][j4+4]);
        float4 p2 = *(const float4*)(&ps[w][j4+8]);
        float4 p3 = *(const float4*)(&ps[w][j4+12]);
        ac0 += p0.x*vls[j4+0][lane] + p0.y*vls[j4+1][lane]
             + p0.z*vls[j4+2][lane] + p0.w*vls[j4+3][lane];
        ac1 += p1.x*vls[j4+4][lane] + p1.y*vls[j4+5][lane]
             + p1.z*vls[j4+6][lane] + p1.w*vls[j4+7][lane];
        ac2 += p2.x*vls[j4+8][lane] + p2.y*vls[j4+9][lane]
             + p2.z*vls[j4+10][lane] + p2.w*vls[j4+11][lane];
        ac3 += p3.x*vls[j4+12][lane] + p3.y*vls[j4+13][lane]
             + p3.z*vls[j4+14][lane] + p3.w*vls[j4+15][lane];
      }
      float accv = ((ac0 + ac1) + (ac2 + ac3)) + ps[w][128]*vls[128][lane];
      o[((size_t)(b*kNT + r))*kC + hh*kHD + lane] = f2bf(accv / sum);
    }
  }
}

// ------------------------------------------------------------- head
__global__ __launch_bounds__(256) void head_kernel(
    const float* __restrict__ xf,
    const float* __restrict__ hw1, const float* __restrict__ hb1,
    const float* __restrict__ hg1, const float* __restrict__ hbe1,
    const float* __restrict__ hw2, const float* __restrict__ hb2,
    const float* __restrict__ hg2, const float* __restrict__ hbe2,
    const float* __restrict__ hw3, const float* __restrict__ hb3,
    float* __restrict__ out)
{
  __shared__ float f[768];
  __shared__ float h1[256], h2[256];
  const int t = threadIdx.x;
  const int b = blockIdx.x;
  const float* xb = xf + (size_t)b*kNT*kC;
  for (int c = t; c < kC; c += 256) {
    f[c] = xb[c];
    float mx = -3.0e38f;
    for (int n = 1; n < kNT; ++n) mx = fmaxf(mx, xb[(size_t)n*kC + c]);
    f[kC + c] = mx;
  }
  __syncthreads();
  {
    float acc = hb1[t];
    for (int k = 0; k < 768; k += 4) {
      float4 wv = *(const float4*)(hw1 + (size_t)t*768 + k);
      float4 fv = *(const float4*)(&f[k]);
      acc += fv.x*wv.x + fv.y*wv.y + fv.z*wv.z + fv.w*wv.w;
    }
    h1[t] = fmaxf(acc*hg1[t] + hbe1[t], 0.0f);
  }
  __syncthreads();
  {
    float acc = hb2[t];
    for (int k = 0; k < 256; k += 4) {
      float4 wv = *(const float4*)(hw2 + (size_t)t*256 + k);
      float4 fv = *(const float4*)(&h1[k]);
      acc += fv.x*wv.x + fv.y*wv.y + fv.z*wv.z + fv.w*wv.w;
    }
    h2[t] = fmaxf(acc*hg2[t] + hbe2[t], 0.0f);
  }
  __syncthreads();
  if (t < 40) {
    float acc = hb3[t];
    for (int k = 0; k < 256; k += 4) {
      float4 wv = *(const float4*)(hw3 + (size_t)t*256 + k);
      float4 fv = *(const float4*)(&h2[k]);
      acc += fv.x*wv.x + fv.y*wv.y + fv.z*wv.z + fv.w*wv.w;
    }
    out[(size_t)b*40 + t] = acc;
  }
}

// ------------------------------------------------------------- launch
extern "C" void kernel_launch(void* const* d_in, const int* in_sizes, int n_in,
                              void* d_out, int out_size, void* d_ws, size_t ws_size,
                              hipStream_t stream) {
  const float* pts     = (const float*)d_in[0];
  const float* enc_w1  = (const float*)d_in[1];
  const float* enc_b1  = (const float*)d_in[2];
  const float* enc_g1  = (const float*)d_in[3];
  const float* enc_be1 = (const float*)d_in[4];
  const float* enc_w2  = (const float*)d_in[5];
  const float* enc_b2  = (const float*)d_in[6];
  const float* enc_w3  = (const float*)d_in[7];
  const float* enc_b3  = (const float*)d_in[8];
  const float* enc_g2  = (const float*)d_in[9];
  const float* enc_be2 = (const float*)d_in[10];
  const float* enc_w4  = (const float*)d_in[11];
  const float* enc_b4  = (const float*)d_in[12];
  const float* cls_tok = (const float*)d_in[13];
  const float* cls_pos = (const float*)d_in[14];
  const float* ln1_g   = (const float*)d_in[15];
  const float* ln1_b   = (const float*)d_in[16];
  const float* qkv_w   = (const float*)d_in[17];
  const float* givens  = (const float*)d_in[18];
  const float* proj_w  = (const float*)d_in[19];
  const float* proj_b  = (const float*)d_in[20];
  const float* ln2_g   = (const float*)d_in[21];
  const float* ln2_b   = (const float*)d_in[22];
  const float* fc1_w   = (const float*)d_in[23];
  const float* fc1_b   = (const float*)d_in[24];
  const float* fc2_w   = (const float*)d_in[25];
  const float* fc2_b   = (const float*)d_in[26];
  const float* norm_g  = (const float*)d_in[27];
  const float* norm_b  = (const float*)d_in[28];
  const float* hw1     = (const float*)d_in[29];
  const float* hb1     = (const float*)d_in[30];
  const float* hg1     = (const float*)d_in[31];
  const float* hbe1    = (const float*)d_in[32];
  const float* hw2     = (const float*)d_in[33];
  const float* hb2     = (const float*)d_in[34];
  const float* hg2     = (const float*)d_in[35];
  const float* hbe2    = (const float*)d_in[36];
  const float* hw3     = (const float*)d_in[37];
  const float* hb3     = (const float*)d_in[38];

  constexpr size_t kWL = 1769472ull;          // per-layer bf16 weight elements
  char* wsb = (char*)d_ws;
  size_t off = 0;
  float* center = (float*)(wsb + off); off += (size_t)kB*kG*3*4;
  float* pcs    = (float*)(wsb + off); off += (size_t)kB*kG*24*4;
  float* psn    = (float*)(wsb + off); off += (size_t)kB*kG*24*4;
  float* neigh  = (float*)(wsb + off); off += (size_t)kB*kG*kM*3*4;
  float* xbuf   = (float*)(wsb + off); off += (size_t)kRows*kC*4;
  unsigned short* encwb = (unsigned short*)(wsb + off); off += 491520ull*2;
  unsigned short* wlbf  = (unsigned short*)(wsb + off);
  const size_t scratchNeed = 16777216ull + 8388608ull + 262144ull + 1048576ull;
  const bool bigws = ws_size >= off + 12*kWL*2 + scratchNeed;
  off += (bigws ? 12*kWL*2 : kWL*2);
  char* scratch = wsb + off;
  // encoder view of scratch (f1c aliases f3c region: disjoint lifetimes)
  unsigned short* f3c   = (unsigned short*)(scratch);
  unsigned short* f1c   = (unsigned short*)(scratch);
  unsigned short* f2c   = (unsigned short*)(scratch + 16777216);
  unsigned short* fgc   = (unsigned short*)(scratch + 16777216 + 8388608);
  float*          basec = (float*)(scratch + 16777216 + 8388608 + 262144);
  // transformer view of scratch (round-4 layout: hbuf + qkvb + attnob; mlpb aliases)
  unsigned short* hbuf   = (unsigned short*)(scratch);
  unsigned short* qkvb   = (unsigned short*)(scratch + 3170304);
  unsigned short* attnob = (unsigned short*)(scratch + 3170304 + 9510912);
  unsigned short* mlpb   = (unsigned short*)(scratch + 3170304);
  float*          flnb   = (float*)(scratch + 3170304);  // post-loop, qkvb dead

  const unsigned short* encw2 = encwb;
  const unsigned short* encw3 = encwb + 32768;
  const unsigned short* encw4 = encwb + 32768 + 262144;

  fps_kernel<<<kB, 64, 0, stream>>>(pts, center);
  rope_kernel<<<(kB*kG*24 + 255)/256, 256, 0, stream>>>(center, pcs, psn);
  knn_kernel<<<kB*kG/4, 256, 0, stream>>>(pts, center, neigh);

  // weight caches
  wcvt_kernel<<<32768/8/256, 256, 0, stream>>>(enc_w2, (unsigned short*)encw2, 32768);
  wcvt_kernel<<<262144/8/256, 256, 0, stream>>>(enc_w3, (unsigned short*)encw3, 262144);
  wcvt_kernel<<<196608/8/256, 256, 0, stream>>>(enc_w4, (unsigned short*)encw4, 196608);
  if (bigws) {
    for (int l = 0; l < 12; ++l)
      wcvt4_kernel<<<864, 256, 0, stream>>>(
          qkv_w + (size_t)l*442368, proj_w + (size_t)l*147456,
          fc1_w + (size_t)l*589824, fc2_w + (size_t)l*589824, wlbf + (size_t)l*kWL);
  }

  // ---- encoder: 8 chunks of 512 groups (16384 rows) ----
  for (int c = 0; c < 8; ++c) {
    const float* nc = neigh + (size_t)c*kRC*3;
    enc1_kernel<<<kRC/2, 256, 0, stream>>>(nc, enc_w1, enc_b1, enc_g1, enc_be1, f1c);
    mgemm_kernel<1,2,2><<<dim3(kRC/64, 4), 256, 0, stream>>>(
        f1c, 128, encw2, 128, f2c, enc_b2, nullptr, nullptr, nullptr,
        kRC, 256, 128, nullptr, 0);
    pool2_kernel<<<kGC, 256, 0, stream>>>(f2c, fgc);
    mgemm_kernel<2,2,2><<<dim3(kGC/64, 8), 256, 0, stream>>>(
        fgc, 256, encw3, 512, basec, enc_b3, nullptr, nullptr, nullptr,
        kGC, 512, 256, nullptr, 0);
    mgemm_kernel<3,2,2><<<dim3(kRC/64, 8), 256, 0, stream>>>(
        f2c, 256, encw3 + 256, 512, f3c, nullptr, basec, enc_g2, enc_be2,
        kRC, 512, 256, nullptr, 0);
    mgemm_kernel<4,2,2><<<dim3(kRC/64, 6), 256, 0, stream>>>(
        f3c, 512, encw4, 512, nullptr, enc_b4, nullptr, nullptr, nullptr,
        kRC, 384, 512, xbuf, c*kGC);
  }
  cls_kernel<<<(kB*kC + 255)/256, 256, 0, stream>>>(cls_tok, cls_pos, xbuf);

  const int lnGrid = kRows/4;
  for (int l = 0; l < 12; ++l) {
    unsigned short* wl = wlbf + (bigws ? (size_t)l*kWL : 0);
    if (!bigws)
      wcvt4_kernel<<<864, 256, 0, stream>>>(
          qkv_w + (size_t)l*442368, proj_w + (size_t)l*147456,
          fc1_w + (size_t)l*589824, fc2_w + (size_t)l*589824, wl);
    const unsigned short* wq  = wl;
    const unsigned short* wp  = wl + 442368;
    const unsigned short* w1f = wl + 589824;
    const unsigned short* w2f = wl + 1179648;
    ln_kernel<1><<<lnGrid, 256, 0, stream>>>(xbuf, hbuf, ln1_g + l*kC, ln1_b + l*kC);
    mgemm_kernel<0,2,2><<<dim3(65, 18), 256, 0, stream>>>(
        hbuf, kC, wq, kC, qkvb, nullptr, nullptr, nullptr, nullptr,
        kRows, 1152, kC, nullptr, 0);
    attn_kernel<<<kB*kH, 512, 0, stream>>>(qkvb, pcs, psn, givens + (size_t)l*kH*24, attnob);
    mgemm_kernel<5,2,2><<<dim3(65, 6), 256, 0, stream>>>(
        attnob, kC, wp, kC, xbuf, proj_b + l*kC, xbuf, nullptr, nullptr,
        kRows, kC, kC, nullptr, 0);
    ln_kernel<1><<<lnGrid, 256, 0, stream>>>(xbuf, hbuf, ln2_g + l*kC, ln2_b + l*kC);
    mgemm_kernel<6,2,2><<<dim3(65, 24), 256, 0, stream>>>(
        hbuf, kC, w1f, kC, mlpb, fc1_b + l*kMLP, nullptr, nullptr, nullptr,
        kRows, kMLP, kC, nullptr, 0);
    mgemm_kernel<5,2,2><<<dim3(65, 6), 256, 0, stream>>>(
        mlpb, kMLP, w2f, kMLP, xbuf, fc2_b + l*kC, xbuf, nullptr, nullptr,
        kRows, kC, kMLP, nullptr, 0);
  }
  ln_kernel<0><<<lnGrid, 256, 0, stream>>>(xbuf, flnb, norm_g, norm_b);
  head_kernel<<<kB, 256, 0, stream>>>(flnb,
      hw1, hb1, hg1, hbe1, hw2, hb2, hg2, hbe2, hw3, hb3, (float*)d_out);
}